// Round 4
// baseline (6426.349 us; speedup 1.0000x reference)
//
#include <hip/hip_runtime.h>
#include <hip/hip_bf16.h>

typedef unsigned short u16;
typedef _Float16 f16;
typedef _Float16 f16x8 __attribute__((ext_vector_type(8)));
typedef short s8v __attribute__((ext_vector_type(8)));
typedef float f4v __attribute__((ext_vector_type(4)));

__device__ __forceinline__ u16 f2bf(float f) {
    union { float f; unsigned u; } v; v.f = f;
    unsigned r = v.u + 0x7FFF + ((v.u >> 16) & 1);
    return (u16)(r >> 16);
}
__device__ __forceinline__ u16 f2h(float f) {
    f16 h = (f16)f;
    union { f16 h; u16 u; } v; v.h = h;
    return v.u;
}
__device__ __forceinline__ float sigm(float x) { return 1.f / (1.f + __expf(-x)); }
__device__ __forceinline__ float fast_tanh(float x) {
    float ax = fabsf(x);
    float e = __expf(2.f * ax);
    float r = 1.f - 2.f / (e + 1.f);   // overflow-safe: e=inf -> r=1
    return copysignf(r, x);
}

// Inline-asm MFMA with explicit operand classes (gfx950: A/B may be AGPR).
// Chains only reuse D as SrcC (0 wait states required). All volatile: the
// source order (kt-major, g-inner) IS the schedule for the 4 chains.
#define MFMA_INIT(D, A, B, C) \
    asm volatile("v_mfma_f32_16x16x32_f16 %0, %1, %2, %3" \
                 : "=v"(D) : "v"(A), "a"(B), "v"(C))
#define MFMA_AG(D, A, B) \
    asm volatile("v_mfma_f32_16x16x32_f16 %0, %1, %2, %0" \
                 : "+v"(D) : "v"(A), "a"(B))

// ---------------------------------------------------------------------------
// Weight prep: transposes to [N][K] bf16 for MFMA B-operand for the GEMMs,
// and packs Ul into f16 MFMA B-fragment layout for the LSTM (8-wave version):
//   512 frags, frag F = tile*8 + kt; tile = w*8 + cg*4 + g  (w in [0,8),
//   cg in [0,2), g in [0,4)); lane l holds 8 f16:
//     B[k][n], k = kt*32 + (l>>4)*8 + j,  n = g*256 + w*32 + cg*16 + (l&15)
//   ALL frags are register-region (64 per wave = 256 AGPRs).
// ---------------------------------------------------------------------------
__global__ __launch_bounds__(256) void prep_kernel(
    const float* __restrict__ Wx, const float* __restrict__ Wc,
    const float* __restrict__ Wl, const float* __restrict__ Wo,
    const float* __restrict__ Ul,
    u16* __restrict__ wxT, u16* __restrict__ wcT, u16* __restrict__ wlT,
    u16* __restrict__ woT, u16* __restrict__ ulB)
{
    int i = blockIdx.x * 256 + threadIdx.x;
    if (i < 65536) {                    // WxT[n][k] : 128x512
        int n = i >> 9, k = i & 511;
        wxT[i] = f2bf(Wx[k * 128 + n]);
    } else if (i < 131072) {            // WcT
        int t = i - 65536;
        int n = t >> 9, k = t & 511;
        wcT[t] = f2bf(Wc[k * 128 + n]);
    } else if (i < 425984) {            // WlT[n][k] : 1024x288 (K padded 257->288)
        int t = i - 131072;
        int n = t / 288, k = t % 288;
        wlT[t] = (k < 257) ? f2bf(Wl[k * 1024 + n]) : (u16)0;
    } else if (i < 491520) {            // WoT[n][k] : 256x256
        int t = i - 425984;
        int n = t >> 8, k = t & 255;
        woT[t] = f2bf(Wo[k * 256 + n]);
    } else {                            // ulB: 512 B-frags f16, i in [491520, 524288)
        int e = i - 491520;             // [0, 32768): one f16x8 element each
        int F = e >> 6, lane = e & 63;
        int m16 = lane & 15, quad = lane >> 4;
        int tile = F >> 3, kt = F & 7;
        int wv = tile >> 3, cg = (tile >> 2) & 1, g = tile & 3;
        int n = g * 256 + wv * 32 + cg * 16 + m16;
        int k0 = kt * 32 + quad * 8;
        u16* o = ulB + (size_t)e * 8;
        #pragma unroll
        for (int jj = 0; jj < 8; ++jj)
            o[jj] = f2h(Ul[(size_t)(k0 + jj) * 1024 + n]);
    }
}

// ---------------------------------------------------------------------------
// s[b,t] = sum_k x[b,t,k]   (one wave per row)
// ---------------------------------------------------------------------------
__global__ __launch_bounds__(256) void row_sums(const float4* __restrict__ x4,
                                                float* __restrict__ s)
{
    int w = threadIdx.x >> 6, lane = threadIdx.x & 63;
    size_t row = (size_t)blockIdx.x * 4 + w;
    const float4* r = x4 + row * 128;
    float4 a = r[lane], b = r[64 + lane];
    float sum = a.x + a.y + a.z + a.w + b.x + b.y + b.z + b.w;
    #pragma unroll
    for (int d = 32; d >= 1; d >>= 1) sum += __shfl_xor(sum, d);
    if (lane == 0) s[row] = sum;
}

// ---------------------------------------------------------------------------
// Count recurrence, 3-phase chunked (8 chunks of 128 steps per batch):
// A: per-chunk zero-init scan -> cend, P=prod(s).  B: combine chunk heads.
// C: re-scan with true c_in, write bf16 x and log1p(count).
// ---------------------------------------------------------------------------
__global__ __launch_bounds__(512) void count_phaseA(const float* __restrict__ x,
                                                    const float* __restrict__ s,
                                                    float* __restrict__ cend,
                                                    float* __restrict__ Pq)
{
    int k = threadIdx.x, bi = blockIdx.x;
    int b = bi >> 3, qc = bi & 7;
    const float* xb = x + ((size_t)b * 1024 + qc * 128) * 512;
    const float* sb = s + b * 1024 + qc * 128;
    float c = 0.f, P = 1.f;
    for (int t0 = 0; t0 < 128; t0 += 8) {
        float xv[8], sv[8];
        #pragma unroll
        for (int i = 0; i < 8; ++i) {
            xv[i] = xb[(size_t)(t0 + i) * 512 + k];
            sv[i] = sb[t0 + i];
        }
        #pragma unroll
        for (int i = 0; i < 8; ++i) { c = sv[i] * c + xv[i]; P *= sv[i]; }
    }
    cend[(size_t)bi * 512 + k] = c;
    if (k == 0) Pq[bi] = P;
}

__global__ __launch_bounds__(512) void count_phaseB(const float* __restrict__ cend,
                                                    const float* __restrict__ Pq,
                                                    float* __restrict__ cin)
{
    int k = threadIdx.x, b = blockIdx.x;
    float c = 0.f;
    for (int q = 0; q < 8; ++q) {
        int bi = b * 8 + q;
        cin[(size_t)bi * 512 + k] = c;
        c = Pq[bi] * c + cend[(size_t)bi * 512 + k];
    }
}

__global__ __launch_bounds__(512) void count_phaseC(const float* __restrict__ x,
                                                    const float* __restrict__ s,
                                                    const float* __restrict__ cin,
                                                    u16* __restrict__ xbf,
                                                    u16* __restrict__ clog)
{
    int k = threadIdx.x, bi = blockIdx.x;
    int b = bi >> 3, qc = bi & 7;
    size_t base = ((size_t)b * 1024 + qc * 128) * 512;
    const float* xb = x + base;
    const float* sb = s + b * 1024 + qc * 128;
    u16* xo = xbf + base;
    u16* co = clog + base;
    float c = cin[(size_t)bi * 512 + k];
    for (int t0 = 0; t0 < 128; t0 += 8) {
        float xv[8], sv[8];
        #pragma unroll
        for (int i = 0; i < 8; ++i) {
            xv[i] = xb[(size_t)(t0 + i) * 512 + k];
            sv[i] = sb[t0 + i];
        }
        #pragma unroll
        for (int i = 0; i < 8; ++i) {
            c = sv[i] * c + xv[i];
            size_t idx = (size_t)(t0 + i) * 512 + k;
            xo[idx] = f2bf(xv[i]);
            co[idx] = f2bf(log1pf(c));
        }
    }
}

// ---------------------------------------------------------------------------
// xc[:,256] = exp(-(delta*Wd+bd)); xc[:,257:288] = 0
// ---------------------------------------------------------------------------
__global__ __launch_bounds__(256) void fill_xc(const float* __restrict__ delta,
                                               const float* __restrict__ Wd,
                                               const float* __restrict__ bd,
                                               u16* __restrict__ xc)
{
    int i = blockIdx.x * 256 + threadIdx.x;   // 65536*32
    int row = i >> 5, cc = i & 31;
    float v = 0.f;
    if (cc == 0) v = __expf(-(delta[row] * Wd[0] + bd[0]));
    xc[(size_t)row * 288 + 256 + cc] = f2bf(v);
}

// ---------------------------------------------------------------------------
// Generic 128x128-tile bf16 MFMA GEMM: C[row, colofs+col] = A@B + bias.
// ---------------------------------------------------------------------------
template <int EPI>
__global__ __launch_bounds__(256) void gemm128(const u16* __restrict__ A,
                                               const u16* __restrict__ BT,
                                               const float* __restrict__ bias,
                                               u16* __restrict__ C,
                                               int K, int ldc, int colofs)
{
    __shared__ u16 Alds[128 * 40];
    __shared__ u16 Blds[128 * 40];
    int tid = threadIdx.x;
    int m0 = blockIdx.x * 128, n0 = blockIdx.y * 128;
    int lane = tid & 63, w = tid >> 6, quad = lane >> 4, m16 = lane & 15;
    int wm = w & 1, wn = w >> 1;
    f4v acc[4][4];
    #pragma unroll
    for (int i = 0; i < 4; ++i)
        #pragma unroll
        for (int j = 0; j < 4; ++j) acc[i][j] = (f4v){0.f, 0.f, 0.f, 0.f};

    for (int k0 = 0; k0 < K; k0 += 32) {
        #pragma unroll
        for (int p = 0; p < 2; ++p) {
            int e = (p * 256 + tid) * 8;
            int r = e >> 5, cc = e & 31;
            *(uint4*)&Alds[r * 40 + cc] =
                *(const uint4*)&A[(size_t)(m0 + r) * K + k0 + cc];
            *(uint4*)&Blds[r * 40 + cc] =
                *(const uint4*)&BT[(size_t)(n0 + r) * K + k0 + cc];
        }
        __syncthreads();
        s8v af[4], bf[4];
        #pragma unroll
        for (int i = 0; i < 4; ++i)
            af[i] = *(const s8v*)&Alds[(wm * 64 + i * 16 + m16) * 40 + quad * 8];
        #pragma unroll
        for (int i = 0; i < 4; ++i)
            bf[i] = *(const s8v*)&Blds[(wn * 64 + i * 16 + m16) * 40 + quad * 8];
        #pragma unroll
        for (int i = 0; i < 4; ++i)
            #pragma unroll
            for (int nj = 0; nj < 4; ++nj)
                acc[i][nj] = __builtin_amdgcn_mfma_f32_16x16x32_bf16(
                    af[i], bf[nj], acc[i][nj], 0, 0, 0);
        __syncthreads();
    }
    #pragma unroll
    for (int nj = 0; nj < 4; ++nj) {
        int col = n0 + wn * 64 + nj * 16 + m16;
        float bv = bias[col];
        #pragma unroll
        for (int i = 0; i < 4; ++i)
            #pragma unroll
            for (int r = 0; r < 4; ++r) {
                int row = m0 + wm * 64 + i * 16 + quad * 4 + r;
                float v = acc[i][nj][r] + bv;
                C[(size_t)row * ldc + colofs + col] = (EPI == 0) ? f2bf(v) : f2h(v);
            }
    }
}

// ---------------------------------------------------------------------------
// LSTM over T=1024 via broadcast-A MFMA GEMV. One block per batch, 512 thr
// (8 waves, 2/SIMD). Wave w owns h-cols [w*32, w*32+32) = 2 clusters (cg)
// of 16 cols x 4 gates = 8 tiles x 8 k-tiles = 64 B-frags = EXACTLY 256
// AGPRs: the whole Ul slice is register-resident, zero per-step LDS weight
// traffic. A-frag = h broadcast (quad k-slice read from LDS, same address
// across the quad's 16 lanes). acc[g][0] on every lane = z[col] for
// col = w*32 + cg*16 + m16; lane keeps cg == (quad&1), so each column's
// gates are computed by two quads (redundant); quads 0,1 store.
// Per-step barrier: s_waitcnt lgkmcnt(0) + s_barrier only (vmem stays in
// flight across it -- pre prefetch and hout stores never drain).
// ---------------------------------------------------------------------------
__global__ __launch_bounds__(512, 2) void lstm_kernel(const f16* __restrict__ pre,
                                                      const u16* __restrict__ ulB,
                                                      u16* __restrict__ hout)
{
    __shared__ f16 hl[2][256];
    const int tid = threadIdx.x, b = blockIdx.x;
    const int w = tid >> 6, lane = tid & 63, quad = lane >> 4, m16 = lane & 15;
    const int cq = quad & 1;                 // which cg this lane extracts
    const int col = w * 32 + cq * 16 + m16;  // this lane's h column

    const f16x8* ub = (const f16x8*)ulB;
    // all 64 frags (cg 0..1, g 0..3, kt 0..7) pinned in AGPRs (1-time copy)
    f16x8 wa[2][4][8];
    #pragma unroll
    for (int cg = 0; cg < 2; ++cg)
        #pragma unroll
        for (int g = 0; g < 4; ++g)
            #pragma unroll
            for (int kt = 0; kt < 8; ++kt) {
                f16x8 tmp = ub[(size_t)(((w * 8 + cg * 4 + g) * 8 + kt) * 64 + lane)];
                asm("" : "=a"(wa[cg][g][kt]) : "0"(tmp));
            }
    const f16* prep_ = pre + (size_t)b * 1024 * 1024;
    const f16* pcol = prep_ + col;          // this lane's gate-column stream
    u16* ho = hout + (size_t)b * 1024 * 256;
    if (tid < 256) hl[0][tid] = (f16)0.f;
    float c = 0.f;
    f16 pcur[4];
    #pragma unroll
    for (int g = 0; g < 4; ++g) pcur[g] = pcol[g * 256];
    f4v z4 = {0.f, 0.f, 0.f, 0.f};
    __syncthreads();

    #pragma unroll 1
    for (int t = 0; t < 1024; ++t) {
        // h k-slices for this quad (broadcast LDS reads)
        const f16* hrow = &hl[t & 1][quad * 8];
        f16x8 av[8];
        #pragma unroll
        for (int kt = 0; kt < 8; ++kt)
            av[kt] = *(const f16x8*)&hrow[kt * 32];
        // prefetch pre[t+1] (stays in flight across the barrier)
        int t1 = (t < 1023) ? (t + 1) : 1023;
        f16 pnext[4];
        #pragma unroll
        for (int g = 0; g < 4; ++g) pnext[g] = pcol[(size_t)t1 * 1024 + g * 256];

        float zq0 = 0.f, zq1 = 0.f, zq2 = 0.f, zq3 = 0.f;
        #pragma unroll
        for (int cg = 0; cg < 2; ++cg) {
            f4v A0, A1, A2, A3;
            MFMA_INIT(A0, av[0], wa[cg][0][0], z4);
            MFMA_INIT(A1, av[0], wa[cg][1][0], z4);
            MFMA_INIT(A2, av[0], wa[cg][2][0], z4);
            MFMA_INIT(A3, av[0], wa[cg][3][0], z4);
            #pragma unroll
            for (int kt = 1; kt < 8; ++kt) {
                MFMA_AG(A0, av[kt], wa[cg][0][kt]);
                MFMA_AG(A1, av[kt], wa[cg][1][kt]);
                MFMA_AG(A2, av[kt], wa[cg][2][kt]);
                MFMA_AG(A3, av[kt], wa[cg][3][kt]);
            }
            // hazard guard: VALU read of MFMA destinations
            asm volatile("s_nop 7\n\ts_nop 7");
            zq0 = (cq == cg) ? A0[0] : zq0;
            zq1 = (cq == cg) ? A1[0] : zq1;
            zq2 = (cq == cg) ? A2[0] : zq2;
            zq3 = (cq == cg) ? A3[0] : zq3;
        }
        // gates (column = col; two quads compute each column redundantly)
        float z0 = zq0 + (float)pcur[0];
        float z1 = zq1 + (float)pcur[1];
        float z2 = zq2 + (float)pcur[2];
        float z3 = zq3 + (float)pcur[3];
        float ig = sigm(z0), fg = sigm(z1);
        float gg = fast_tanh(z2), og = sigm(z3);
        c = fg * c + ig * gg;
        float hs = og * fast_tanh(c);
        if (quad < 2) {
            hl[(t + 1) & 1][col] = (f16)hs;
            ho[(size_t)t * 256 + col] = f2bf(hs);   // fire-and-forget
        }
        #pragma unroll
        for (int g = 0; g < 4; ++g) pcur[g] = pnext[g];
        // raw barrier: drain LDS only; vmem ops continue across
        asm volatile("s_waitcnt lgkmcnt(0)\n\ts_barrier" ::: "memory");
    }
}

// ---------------------------------------------------------------------------
// out[row] = sum_n sigmoid(h[row]@Wo[:,n] + bo[n]) * q[row,n]
// ---------------------------------------------------------------------------
__global__ __launch_bounds__(256) void gemm_out(const u16* __restrict__ H,
                                                const u16* __restrict__ woT,
                                                const float* __restrict__ bo,
                                                const float* __restrict__ q,
                                                float* __restrict__ out)
{
    __shared__ u16 Alds[64 * 40];
    __shared__ u16 Blds[256 * 40];
    __shared__ float red[64][4];
    int tid = threadIdx.x;
    int m0 = blockIdx.x * 64;
    int lane = tid & 63, w = tid >> 6, quad = lane >> 4, m16 = lane & 15;
    f4v acc[4][4];
    #pragma unroll
    for (int i = 0; i < 4; ++i)
        #pragma unroll
        for (int j = 0; j < 4; ++j) acc[i][j] = (f4v){0.f, 0.f, 0.f, 0.f};

    for (int k0 = 0; k0 < 256; k0 += 32) {
        {
            int e = tid * 8;
            int r = e >> 5, cc = e & 31;
            *(uint4*)&Alds[r * 40 + cc] =
                *(const uint4*)&H[(size_t)(m0 + r) * 256 + k0 + cc];
        }
        #pragma unroll
        for (int p = 0; p < 4; ++p) {
            int e = (p * 256 + tid) * 8;
            int r = e >> 5, cc = e & 31;
            *(uint4*)&Blds[r * 40 + cc] =
                *(const uint4*)&woT[(size_t)r * 256 + k0 + cc];
        }
        __syncthreads();
        s8v af[4], bf[4];
        #pragma unroll
        for (int i = 0; i < 4; ++i)
            af[i] = *(const s8v*)&Alds[(i * 16 + m16) * 40 + quad * 8];
        #pragma unroll
        for (int i = 0; i < 4; ++i)
            bf[i] = *(const s8v*)&Blds[(w * 64 + i * 16 + m16) * 40 + quad * 8];
        #pragma unroll
        for (int i = 0; i < 4; ++i)
            #pragma unroll
            for (int nj = 0; nj < 4; ++nj)
                acc[i][nj] = __builtin_amdgcn_mfma_f32_16x16x32_bf16(
                    af[i], bf[nj], acc[i][nj], 0, 0, 0);
        __syncthreads();
    }
    float rsum[4][4];
    #pragma unroll
    for (int i = 0; i < 4; ++i)
        #pragma unroll
        for (int r = 0; r < 4; ++r) rsum[i][r] = 0.f;
    #pragma unroll
    for (int nj = 0; nj < 4; ++nj) {
        int col = w * 64 + nj * 16 + m16;
        float bv = bo[col];
        #pragma unroll
        for (int i = 0; i < 4; ++i)
            #pragma unroll
            for (int r = 0; r < 4; ++r) {
                int row = m0 + i * 16 + quad * 4 + r;
                float v = sigm(acc[i][nj][r] + bv);
                rsum[i][r] += v * q[(size_t)row * 256 + col];
            }
    }
    #pragma unroll
    for (int d = 1; d <= 8; d <<= 1)
        #pragma unroll
        for (int i = 0; i < 4; ++i)
            #pragma unroll
            for (int r = 0; r < 4; ++r) rsum[i][r] += __shfl_xor(rsum[i][r], d);
    if (m16 == 0) {
        #pragma unroll
        for (int i = 0; i < 4; ++i)
            #pragma unroll
            for (int r = 0; r < 4; ++r)
                red[i * 16 + quad * 4 + r][w] = rsum[i][r];
    }
    __syncthreads();
    if (tid < 64)
        out[m0 + tid] = red[tid][0] + red[tid][1] + red[tid][2] + red[tid][3];
}

// ---------------------------------------------------------------------------
extern "C" void kernel_launch(void* const* d_in, const int* in_sizes, int n_in,
                              void* d_out, int out_size, void* d_ws, size_t ws_size,
                              hipStream_t stream)
{
    (void)in_sizes; (void)n_in; (void)out_size; (void)ws_size;
    const float* x     = (const float*)d_in[0];
    const float* delta = (const float*)d_in[1];
    const float* q     = (const float*)d_in[2];
    const float* Wx    = (const float*)d_in[3];
    const float* bx    = (const float*)d_in[4];
    const float* Wc    = (const float*)d_in[5];
    const float* bc    = (const float*)d_in[6];
    const float* Wd    = (const float*)d_in[7];
    const float* bd    = (const float*)d_in[8];
    const float* Wl    = (const float*)d_in[9];
    const float* Ul    = (const float*)d_in[10];
    const float* bl    = (const float*)d_in[11];
    const float* Wo    = (const float*)d_in[12];
    const float* bo    = (const float*)d_in[13];

    char* ws = (char*)d_ws;
    float* s_buf = (float*)(ws + 0);            // 256 KB
    u16* ulB     = (u16*)(ws + 262144);         // 512 KB (B-frag layout f16)
    u16* wxT     = (u16*)(ws + 786432);         // 128 KB
    u16* wcT     = (u16*)(ws + 917504);         // 128 KB
    u16* wlT     = (u16*)(ws + 1048576);        // 576 KB
    u16* woT     = (u16*)(ws + 1638400);        // 128 KB
    u16* xc      = (u16*)(ws + 1769472);        // 36 MB  [65536 x 288] bf16
    u16* hbuf    = (u16*)(ws + 39518208);       // 32 MB  [65536 x 256] bf16
    u16* xbf     = (u16*)(ws + 73072640);       // 64 MB  bf16 copy of x
    u16* clog    = (u16*)(ws + 140181504);      // 64 MB  log1p(counts) bf16
    f16* pre     = (f16*)(ws + 73072640);       // 128 MB f16, aliases xbf+clog
    // count-scan scratch lives in the (not yet used) hbuf region
    float* cend  = (float*)hbuf;                // 1 MB
    float* cin   = (float*)(ws + 39518208 + (1 << 20));   // 1 MB
    float* Pq    = (float*)(ws + 39518208 + (2 << 20));   // 2 KB

    prep_kernel<<<2048, 256, 0, stream>>>(Wx, Wc, Wl, Wo, Ul, wxT, wcT, wlT, woT, ulB);
    row_sums<<<16384, 256, 0, stream>>>((const float4*)x, s_buf);
    count_phaseA<<<512, 512, 0, stream>>>(x, s_buf, cend, Pq);
    count_phaseB<<<64, 512, 0, stream>>>(cend, Pq, cin);
    count_phaseC<<<512, 512, 0, stream>>>(x, s_buf, cin, xbf, clog);
    fill_xc<<<8192, 256, 0, stream>>>(delta, Wd, bd, xc);
    gemm128<0><<<dim3(512, 1), 256, 0, stream>>>(xbf, wxT, bx, xc, 512, 288, 0);
    gemm128<0><<<dim3(512, 1), 256, 0, stream>>>(clog, wcT, bc, xc, 512, 288, 128);
    gemm128<1><<<dim3(512, 8), 256, 0, stream>>>(xc, wlT, bl, (u16*)pre, 288, 1024, 0);
    lstm_kernel<<<64, 512, 0, stream>>>(pre, ulB, hbuf);
    gemm_out<<<1024, 256, 0, stream>>>(hbuf, woT, bo, q, (float*)d_out);
}

// Round 6
// 5331.259 us; speedup vs baseline: 1.2054x; 1.2054x over previous
//
#include <hip/hip_runtime.h>
#include <hip/hip_bf16.h>

typedef unsigned short u16;
typedef _Float16 f16;
typedef _Float16 f16x8 __attribute__((ext_vector_type(8)));
typedef short s8v __attribute__((ext_vector_type(8)));
typedef float f4v __attribute__((ext_vector_type(4)));

__device__ __forceinline__ u16 f2bf(float f) {
    union { float f; unsigned u; } v; v.f = f;
    unsigned r = v.u + 0x7FFF + ((v.u >> 16) & 1);
    return (u16)(r >> 16);
}
__device__ __forceinline__ u16 f2h(float f) {
    f16 h = (f16)f;
    union { f16 h; u16 u; } v; v.h = h;
    return v.u;
}
__device__ __forceinline__ float sigm(float x) { return 1.f / (1.f + __expf(-x)); }
__device__ __forceinline__ float fast_tanh(float x) {
    float ax = fabsf(x);
    float e = __expf(2.f * ax);
    float r = 1.f - 2.f / (e + 1.f);   // overflow-safe: e=inf -> r=1
    return copysignf(r, x);
}

// Inline-asm MFMA with explicit operand classes (gfx950: A/B may be AGPR).
// Chains only reuse D as SrcC (0 wait states required).
#define MFMA_INIT(D, A, B, C) \
    asm volatile("v_mfma_f32_16x16x32_f16 %0, %1, %2, %3" \
                 : "=v"(D) : "v"(A), "a"(B), "v"(C))
#define MFMA_AG(D, A, B) \
    asm volatile("v_mfma_f32_16x16x32_f16 %0, %1, %2, %0" \
                 : "+v"(D) : "v"(A), "a"(B))
#define MFMA_VG(D, A, B) \
    asm volatile("v_mfma_f32_16x16x32_f16 %0, %1, %2, %0" \
                 : "+v"(D) : "v"(A), "v"(B))

// ---------------------------------------------------------------------------
// Weight prep: transposes to [N][K] bf16 for MFMA B-operand for the GEMMs,
// and packs Ul into f16 MFMA B-fragment layout for the LSTM:
//   512 frags; lane l holds 8 f16 of B[k][n]:
//     k = kt*32 + (l>>4)*8 + j,  n = g*256 + w*64 + cg*16 + (l&15)
//   Region R (AGPR, kt 0..3): F = (w*16 + cg*4 + g)*4 + kt          (F < 256)
//   Region S (L2 stream, kt 4..7): F = 256 + (w*4+cg)*16 + g*4 + (kt-4)
//   Region S is contiguous per (w,cg) so the per-step reload is 16
//   fully-coalesced dwordx4 loads with small offsets.
// ---------------------------------------------------------------------------
__global__ __launch_bounds__(256) void prep_kernel(
    const float* __restrict__ Wx, const float* __restrict__ Wc,
    const float* __restrict__ Wl, const float* __restrict__ Wo,
    const float* __restrict__ Ul,
    u16* __restrict__ wxT, u16* __restrict__ wcT, u16* __restrict__ wlT,
    u16* __restrict__ woT, u16* __restrict__ ulB)
{
    int i = blockIdx.x * 256 + threadIdx.x;
    if (i < 65536) {                    // WxT[n][k] : 128x512
        int n = i >> 9, k = i & 511;
        wxT[i] = f2bf(Wx[k * 128 + n]);
    } else if (i < 131072) {            // WcT
        int t = i - 65536;
        int n = t >> 9, k = t & 511;
        wcT[t] = f2bf(Wc[k * 128 + n]);
    } else if (i < 425984) {            // WlT[n][k] : 1024x288 (K padded 257->288)
        int t = i - 131072;
        int n = t / 288, k = t % 288;
        wlT[t] = (k < 257) ? f2bf(Wl[k * 1024 + n]) : (u16)0;
    } else if (i < 491520) {            // WoT[n][k] : 256x256
        int t = i - 425984;
        int n = t >> 8, k = t & 255;
        woT[t] = f2bf(Wo[k * 256 + n]);
    } else {                            // ulB: 512 B-frags f16, i in [491520, 524288)
        int e = i - 491520;             // [0, 32768): one f16x8 element each
        int F = e >> 6, lane = e & 63;
        int m16 = lane & 15, quad = lane >> 4;
        int w, cg, g, kt;
        if (F < 256) {                  // region R: kt 0..3
            int tile = F >> 2; kt = F & 3;
            w = tile >> 4; cg = (tile >> 2) & 3; g = tile & 3;
        } else {                        // region S: kt 4..7
            int L = F - 256;
            int wcg = L >> 4, rem = L & 15;
            g = rem >> 2; kt = 4 + (rem & 3);
            w = wcg >> 2; cg = wcg & 3;
        }
        int n = g * 256 + w * 64 + cg * 16 + m16;
        int k0 = kt * 32 + quad * 8;
        u16* o = ulB + (size_t)e * 8;
        #pragma unroll
        for (int jj = 0; jj < 8; ++jj)
            o[jj] = f2h(Ul[(size_t)(k0 + jj) * 1024 + n]);
    }
}

// ---------------------------------------------------------------------------
// s[b,t] = sum_k x[b,t,k]   (one wave per row)
// ---------------------------------------------------------------------------
__global__ __launch_bounds__(256) void row_sums(const float4* __restrict__ x4,
                                                float* __restrict__ s)
{
    int w = threadIdx.x >> 6, lane = threadIdx.x & 63;
    size_t row = (size_t)blockIdx.x * 4 + w;
    const float4* r = x4 + row * 128;
    float4 a = r[lane], b = r[64 + lane];
    float sum = a.x + a.y + a.z + a.w + b.x + b.y + b.z + b.w;
    #pragma unroll
    for (int d = 32; d >= 1; d >>= 1) sum += __shfl_xor(sum, d);
    if (lane == 0) s[row] = sum;
}

// ---------------------------------------------------------------------------
// Count recurrence, 3-phase chunked (8 chunks of 128 steps per batch).
// ---------------------------------------------------------------------------
__global__ __launch_bounds__(512) void count_phaseA(const float* __restrict__ x,
                                                    const float* __restrict__ s,
                                                    float* __restrict__ cend,
                                                    float* __restrict__ Pq)
{
    int k = threadIdx.x, bi = blockIdx.x;
    int b = bi >> 3, qc = bi & 7;
    const float* xb = x + ((size_t)b * 1024 + qc * 128) * 512;
    const float* sb = s + b * 1024 + qc * 128;
    float c = 0.f, P = 1.f;
    for (int t0 = 0; t0 < 128; t0 += 8) {
        float xv[8], sv[8];
        #pragma unroll
        for (int i = 0; i < 8; ++i) {
            xv[i] = xb[(size_t)(t0 + i) * 512 + k];
            sv[i] = sb[t0 + i];
        }
        #pragma unroll
        for (int i = 0; i < 8; ++i) { c = sv[i] * c + xv[i]; P *= sv[i]; }
    }
    cend[(size_t)bi * 512 + k] = c;
    if (k == 0) Pq[bi] = P;
}

__global__ __launch_bounds__(512) void count_phaseB(const float* __restrict__ cend,
                                                    const float* __restrict__ Pq,
                                                    float* __restrict__ cin)
{
    int k = threadIdx.x, b = blockIdx.x;
    float c = 0.f;
    for (int q = 0; q < 8; ++q) {
        int bi = b * 8 + q;
        cin[(size_t)bi * 512 + k] = c;
        c = Pq[bi] * c + cend[(size_t)bi * 512 + k];
    }
}

__global__ __launch_bounds__(512) void count_phaseC(const float* __restrict__ x,
                                                    const float* __restrict__ s,
                                                    const float* __restrict__ cin,
                                                    u16* __restrict__ xbf,
                                                    u16* __restrict__ clog)
{
    int k = threadIdx.x, bi = blockIdx.x;
    int b = bi >> 3, qc = bi & 7;
    size_t base = ((size_t)b * 1024 + qc * 128) * 512;
    const float* xb = x + base;
    const float* sb = s + b * 1024 + qc * 128;
    u16* xo = xbf + base;
    u16* co = clog + base;
    float c = cin[(size_t)bi * 512 + k];
    for (int t0 = 0; t0 < 128; t0 += 8) {
        float xv[8], sv[8];
        #pragma unroll
        for (int i = 0; i < 8; ++i) {
            xv[i] = xb[(size_t)(t0 + i) * 512 + k];
            sv[i] = sb[t0 + i];
        }
        #pragma unroll
        for (int i = 0; i < 8; ++i) {
            c = sv[i] * c + xv[i];
            size_t idx = (size_t)(t0 + i) * 512 + k;
            xo[idx] = f2bf(xv[i]);
            co[idx] = f2bf(log1pf(c));
        }
    }
}

// ---------------------------------------------------------------------------
// xc[:,256] = exp(-(delta*Wd+bd)); xc[:,257:288] = 0
// ---------------------------------------------------------------------------
__global__ __launch_bounds__(256) void fill_xc(const float* __restrict__ delta,
                                               const float* __restrict__ Wd,
                                               const float* __restrict__ bd,
                                               u16* __restrict__ xc)
{
    int i = blockIdx.x * 256 + threadIdx.x;   // 65536*32
    int row = i >> 5, cc = i & 31;
    float v = 0.f;
    if (cc == 0) v = __expf(-(delta[row] * Wd[0] + bd[0]));
    xc[(size_t)row * 288 + 256 + cc] = f2bf(v);
}

// ---------------------------------------------------------------------------
// Generic 128x128-tile bf16 MFMA GEMM: C[row, colofs+col] = A@B + bias.
// ---------------------------------------------------------------------------
template <int EPI>
__global__ __launch_bounds__(256) void gemm128(const u16* __restrict__ A,
                                               const u16* __restrict__ BT,
                                               const float* __restrict__ bias,
                                               u16* __restrict__ C,
                                               int K, int ldc, int colofs)
{
    __shared__ u16 Alds[128 * 40];
    __shared__ u16 Blds[128 * 40];
    int tid = threadIdx.x;
    int m0 = blockIdx.x * 128, n0 = blockIdx.y * 128;
    int lane = tid & 63, w = tid >> 6, quad = lane >> 4, m16 = lane & 15;
    int wm = w & 1, wn = w >> 1;
    f4v acc[4][4];
    #pragma unroll
    for (int i = 0; i < 4; ++i)
        #pragma unroll
        for (int j = 0; j < 4; ++j) acc[i][j] = (f4v){0.f, 0.f, 0.f, 0.f};

    for (int k0 = 0; k0 < K; k0 += 32) {
        #pragma unroll
        for (int p = 0; p < 2; ++p) {
            int e = (p * 256 + tid) * 8;
            int r = e >> 5, cc = e & 31;
            *(uint4*)&Alds[r * 40 + cc] =
                *(const uint4*)&A[(size_t)(m0 + r) * K + k0 + cc];
            *(uint4*)&Blds[r * 40 + cc] =
                *(const uint4*)&BT[(size_t)(n0 + r) * K + k0 + cc];
        }
        __syncthreads();
        s8v af[4], bf[4];
        #pragma unroll
        for (int i = 0; i < 4; ++i)
            af[i] = *(const s8v*)&Alds[(wm * 64 + i * 16 + m16) * 40 + quad * 8];
        #pragma unroll
        for (int i = 0; i < 4; ++i)
            bf[i] = *(const s8v*)&Blds[(wn * 64 + i * 16 + m16) * 40 + quad * 8];
        #pragma unroll
        for (int i = 0; i < 4; ++i)
            #pragma unroll
            for (int nj = 0; nj < 4; ++nj)
                acc[i][nj] = __builtin_amdgcn_mfma_f32_16x16x32_bf16(
                    af[i], bf[nj], acc[i][nj], 0, 0, 0);
        __syncthreads();
    }
    #pragma unroll
    for (int nj = 0; nj < 4; ++nj) {
        int col = n0 + wn * 64 + nj * 16 + m16;
        float bv = bias[col];
        #pragma unroll
        for (int i = 0; i < 4; ++i)
            #pragma unroll
            for (int r = 0; r < 4; ++r) {
                int row = m0 + wm * 64 + i * 16 + quad * 4 + r;
                float v = acc[i][nj][r] + bv;
                C[(size_t)row * ldc + colofs + col] = (EPI == 0) ? f2bf(v) : f2h(v);
            }
    }
}

// ---------------------------------------------------------------------------
// LSTM over T=1024 via broadcast-A MFMA GEMV. One block per batch, 256 thr
// (4 waves, 1/SIMD, full 512-reg budget). Wave w owns h-cols [w*64,w*64+64)
// = 4 clusters (cg) of 16 cols x 4 gates. Weight residency:
//   kt 0..3 -> 64 frags pinned in AGPRs (exactly 256)
//   kt 4..7 -> streamed from L2 every step (ulB is 512 KB, XCD-L2-resident;
//              re-read per step on the VMEM pipe, NOT the LDS pipe).
// Stream is double-buffered (wbA/wbB, 16 frags each): buffer consumed at cg
// is reloaded for cg+2 right after, ~2 cg-bodies (~300cy) ahead of next use,
// covering L2 latency. Compiler inserts precise vmcnt before consuming MFMA.
// LDS carries only the 8 broadcast h k-slice reads + h write per step.
// Per-step barrier: s_waitcnt lgkmcnt(0) + s_barrier only (vmem in flight).
// ---------------------------------------------------------------------------
#define CG_BODY(CG, BUF)                                               \
    {                                                                  \
        f4v A0, A1, A2, A3;                                            \
        MFMA_INIT(A0, av[0], wa[CG][0][0], z4);                        \
        MFMA_INIT(A1, av[0], wa[CG][1][0], z4);                        \
        MFMA_INIT(A2, av[0], wa[CG][2][0], z4);                        \
        MFMA_INIT(A3, av[0], wa[CG][3][0], z4);                        \
        _Pragma("unroll")                                              \
        for (int kt = 1; kt < 4; ++kt) {                               \
            MFMA_AG(A0, av[kt], wa[CG][0][kt]);                        \
            MFMA_AG(A1, av[kt], wa[CG][1][kt]);                        \
            MFMA_AG(A2, av[kt], wa[CG][2][kt]);                        \
            MFMA_AG(A3, av[kt], wa[CG][3][kt]);                        \
        }                                                              \
        _Pragma("unroll")                                              \
        for (int kk = 0; kk < 4; ++kk) {                               \
            MFMA_VG(A0, av[4 + kk], BUF[0 * 4 + kk]);                  \
            MFMA_VG(A1, av[4 + kk], BUF[1 * 4 + kk]);                  \
            MFMA_VG(A2, av[4 + kk], BUF[2 * 4 + kk]);                  \
            MFMA_VG(A3, av[4 + kk], BUF[3 * 4 + kk]);                  \
        }                                                              \
        asm volatile("s_nop 7\n\ts_nop 7");                            \
        zq0 = (quad == CG) ? A0[0] : zq0;                              \
        zq1 = (quad == CG) ? A1[0] : zq1;                              \
        zq2 = (quad == CG) ? A2[0] : zq2;                              \
        zq3 = (quad == CG) ? A3[0] : zq3;                              \
    }
#define RELOAD(BUF, RC)                                                \
    _Pragma("unroll")                                                  \
    for (int j = 0; j < 16; ++j)                                       \
        BUF[j] = ubs[(size_t)(((w * 4 + (RC)) * 16 + j) * 64 + lane)];

__global__ __launch_bounds__(256, 1) void lstm_kernel(const f16* __restrict__ pre,
                                                      const u16* __restrict__ ulB,
                                                      u16* __restrict__ hout)
{
    __shared__ f16 hl[2][256];
    const int tid = threadIdx.x, b = blockIdx.x;
    const int w = tid >> 6, lane = tid & 63, quad = lane >> 4;

    const f16x8* ub = (const f16x8*)ulB;
    // kt 0..3 pinned in AGPRs (64 frags = 256 AGPRs, one-time copy)
    f16x8 wa[4][4][4];
    #pragma unroll
    for (int cg = 0; cg < 4; ++cg)
        #pragma unroll
        for (int g = 0; g < 4; ++g)
            #pragma unroll
            for (int kt = 0; kt < 4; ++kt) {
                f16x8 tmp = ub[(size_t)(((w * 16 + cg * 4 + g) * 4 + kt) * 64 + lane)];
                asm("" : "=a"(wa[cg][g][kt]) : "0"(tmp));
            }
    const f16x8* ubs = ub + 256 * 64;       // stream region (kt 4..7)

    const f16* prep_ = pre + (size_t)b * 1024 * 1024;
    const f16* pcol = prep_ + tid;          // lane's column stream (col = tid)
    u16* ho = hout + (size_t)b * 1024 * 256;
    hl[0][tid & 255] = (f16)0.f;
    float c = 0.f;
    f16 pcur[4];
    #pragma unroll
    for (int g = 0; g < 4; ++g) pcur[g] = pcol[g * 256];
    f4v z4 = {0.f, 0.f, 0.f, 0.f};

    // prologue: fill stream buffers with cg0 / cg1 frags
    f16x8 wbA[16], wbB[16];
    RELOAD(wbA, 0);
    RELOAD(wbB, 1);
    __syncthreads();

    #pragma unroll 1
    for (int t = 0; t < 1024; ++t) {
        const int cur = t & 1;
        // h k-slices for this quad (broadcast LDS reads)
        f16x8 av[8];
        #pragma unroll
        for (int kt = 0; kt < 8; ++kt)
            av[kt] = *(const f16x8*)&hl[cur][kt * 32 + quad * 8];
        // prefetch pre[t+1] (stays in flight across the barrier)
        int t1 = (t < 1023) ? (t + 1) : 1023;
        f16 pnext[4];
        #pragma unroll
        for (int g = 0; g < 4; ++g) pnext[g] = pcol[(size_t)t1 * 1024 + g * 256];

        float zq0 = 0.f, zq1 = 0.f, zq2 = 0.f, zq3 = 0.f;
        CG_BODY(0, wbA); RELOAD(wbA, 2);    // wbA: cg0 -> cg2
        CG_BODY(1, wbB); RELOAD(wbB, 3);    // wbB: cg1 -> cg3
        CG_BODY(2, wbA); RELOAD(wbA, 0);    // wbA: cg2 -> cg0 (next step)
        CG_BODY(3, wbB); RELOAD(wbB, 1);    // wbB: cg3 -> cg1 (next step)

        // gates, once per lane (column = tid)
        float z0 = zq0 + (float)pcur[0];
        float z1 = zq1 + (float)pcur[1];
        float z2 = zq2 + (float)pcur[2];
        float z3 = zq3 + (float)pcur[3];
        float ig = sigm(z0), fg = sigm(z1);
        float gg = fast_tanh(z2), og = sigm(z3);
        c = fg * c + ig * gg;
        float hs = og * fast_tanh(c);
        hl[cur ^ 1][tid & 255] = (f16)hs;
        ho[(size_t)t * 256 + tid] = f2bf(hs);       // fire-and-forget
        #pragma unroll
        for (int g = 0; g < 4; ++g) pcur[g] = pnext[g];
        // raw barrier: drain LDS only; vmem ops continue across
        asm volatile("s_waitcnt lgkmcnt(0)\n\ts_barrier" ::: "memory");
    }
}

// ---------------------------------------------------------------------------
// out[row] = sum_n sigmoid(h[row]@Wo[:,n] + bo[n]) * q[row,n]
// ---------------------------------------------------------------------------
__global__ __launch_bounds__(256) void gemm_out(const u16* __restrict__ H,
                                                const u16* __restrict__ woT,
                                                const float* __restrict__ bo,
                                                const float* __restrict__ q,
                                                float* __restrict__ out)
{
    __shared__ u16 Alds[64 * 40];
    __shared__ u16 Blds[256 * 40];
    __shared__ float red[64][4];
    int tid = threadIdx.x;
    int m0 = blockIdx.x * 64;
    int lane = tid & 63, w = tid >> 6, quad = lane >> 4, m16 = lane & 15;
    f4v acc[4][4];
    #pragma unroll
    for (int i = 0; i < 4; ++i)
        #pragma unroll
        for (int j = 0; j < 4; ++j) acc[i][j] = (f4v){0.f, 0.f, 0.f, 0.f};

    for (int k0 = 0; k0 < 256; k0 += 32) {
        {
            int e = tid * 8;
            int r = e >> 5, cc = e & 31;
            *(uint4*)&Alds[r * 40 + cc] =
                *(const uint4*)&H[(size_t)(m0 + r) * 256 + k0 + cc];
        }
        #pragma unroll
        for (int p = 0; p < 4; ++p) {
            int e = (p * 256 + tid) * 8;
            int r = e >> 5, cc = e & 31;
            *(uint4*)&Blds[r * 40 + cc] =
                *(const uint4*)&woT[(size_t)r * 256 + k0 + cc];
        }
        __syncthreads();
        s8v af[4], bf[4];
        #pragma unroll
        for (int i = 0; i < 4; ++i)
            af[i] = *(const s8v*)&Alds[(i * 16 + m16) * 40 + quad * 8];
        #pragma unroll
        for (int i = 0; i < 4; ++i)
            bf[i] = *(const s8v*)&Blds[(w * 64 + i * 16 + m16) * 40 + quad * 8];
        #pragma unroll
        for (int i = 0; i < 4; ++i)
            #pragma unroll
            for (int nj = 0; nj < 4; ++nj)
                acc[i][nj] = __builtin_amdgcn_mfma_f32_16x16x32_bf16(
                    af[i], bf[nj], acc[i][nj], 0, 0, 0);
        __syncthreads();
    }
    float rsum[4][4];
    #pragma unroll
    for (int i = 0; i < 4; ++i)
        #pragma unroll
        for (int r = 0; r < 4; ++r) rsum[i][r] = 0.f;
    #pragma unroll
    for (int nj = 0; nj < 4; ++nj) {
        int col = w * 64 + nj * 16 + m16;
        float bv = bo[col];
        #pragma unroll
        for (int i = 0; i < 4; ++i)
            #pragma unroll
            for (int r = 0; r < 4; ++r) {
                int row = m0 + i * 16 + quad * 4 + r;
                float v = sigm(acc[i][nj][r] + bv);
                rsum[i][r] += v * q[(size_t)row * 256 + col];
            }
    }
    #pragma unroll
    for (int d = 1; d <= 8; d <<= 1)
        #pragma unroll
        for (int i = 0; i < 4; ++i)
            #pragma unroll
            for (int r = 0; r < 4; ++r) rsum[i][r] += __shfl_xor(rsum[i][r], d);
    if (m16 == 0) {
        #pragma unroll
        for (int i = 0; i < 4; ++i)
            #pragma unroll
            for (int r = 0; r < 4; ++r)
                red[i * 16 + quad * 4 + r][w] = rsum[i][r];
    }
    __syncthreads();
    if (tid < 64)
        out[m0 + tid] = red[tid][0] + red[tid][1] + red[tid][2] + red[tid][3];
}

// ---------------------------------------------------------------------------
extern "C" void kernel_launch(void* const* d_in, const int* in_sizes, int n_in,
                              void* d_out, int out_size, void* d_ws, size_t ws_size,
                              hipStream_t stream)
{
    (void)in_sizes; (void)n_in; (void)out_size; (void)ws_size;
    const float* x     = (const float*)d_in[0];
    const float* delta = (const float*)d_in[1];
    const float* q     = (const float*)d_in[2];
    const float* Wx    = (const float*)d_in[3];
    const float* bx    = (const float*)d_in[4];
    const float* Wc    = (const float*)d_in[5];
    const float* bc    = (const float*)d_in[6];
    const float* Wd    = (const float*)d_in[7];
    const float* bd    = (const float*)d_in[8];
    const float* Wl    = (const float*)d_in[9];
    const float* Ul    = (const float*)d_in[10];
    const float* bl    = (const float*)d_in[11];
    const float* Wo    = (const float*)d_in[12];
    const float* bo    = (const float*)d_in[13];

    char* ws = (char*)d_ws;
    float* s_buf = (float*)(ws + 0);            // 256 KB
    u16* ulB     = (u16*)(ws + 262144);         // 512 KB (B-frag layout f16)
    u16* wxT     = (u16*)(ws + 786432);         // 128 KB
    u16* wcT     = (u16*)(ws + 917504);         // 128 KB
    u16* wlT     = (u16*)(ws + 1048576);        // 576 KB
    u16* woT     = (u16*)(ws + 1638400);        // 128 KB
    u16* xc      = (u16*)(ws + 1769472);        // 36 MB  [65536 x 288] bf16
    u16* hbuf    = (u16*)(ws + 39518208);       // 32 MB  [65536 x 256] bf16
    u16* xbf     = (u16*)(ws + 73072640);       // 64 MB  bf16 copy of x
    u16* clog    = (u16*)(ws + 140181504);      // 64 MB  log1p(counts) bf16
    f16* pre     = (f16*)(ws + 73072640);       // 128 MB f16, aliases xbf+clog
    // count-scan scratch lives in the (not yet used) hbuf region
    float* cend  = (float*)hbuf;                // 1 MB
    float* cin   = (float*)(ws + 39518208 + (1 << 20));   // 1 MB
    float* Pq    = (float*)(ws + 39518208 + (2 << 20));   // 2 KB

    prep_kernel<<<2048, 256, 0, stream>>>(Wx, Wc, Wl, Wo, Ul, wxT, wcT, wlT, woT, ulB);
    row_sums<<<16384, 256, 0, stream>>>((const float4*)x, s_buf);
    count_phaseA<<<512, 512, 0, stream>>>(x, s_buf, cend, Pq);
    count_phaseB<<<64, 512, 0, stream>>>(cend, Pq, cin);
    count_phaseC<<<512, 512, 0, stream>>>(x, s_buf, cin, xbf, clog);
    fill_xc<<<8192, 256, 0, stream>>>(delta, Wd, bd, xc);
    gemm128<0><<<dim3(512, 1), 256, 0, stream>>>(xbf, wxT, bx, xc, 512, 288, 0);
    gemm128<0><<<dim3(512, 1), 256, 0, stream>>>(clog, wcT, bc, xc, 512, 288, 128);
    gemm128<1><<<dim3(512, 8), 256, 0, stream>>>(xc, wlT, bl, (u16*)pre, 288, 1024, 0);
    lstm_kernel<<<64, 256, 0, stream>>>(pre, ulB, hbuf);
    gemm_out<<<1024, 256, 0, stream>>>(hbuf, woT, bo, q, (float*)d_out);
}

// Round 7
// 1867.672 us; speedup vs baseline: 3.4408x; 2.8545x over previous
//
#include <hip/hip_runtime.h>
#include <hip/hip_bf16.h>

typedef unsigned short u16;
typedef long i64;
typedef _Float16 f16;
typedef _Float16 f16x8 __attribute__((ext_vector_type(8)));
typedef short s8v __attribute__((ext_vector_type(8)));
typedef float f4v __attribute__((ext_vector_type(4)));

__device__ __forceinline__ u16 f2bf(float f) {
    union { float f; unsigned u; } v; v.f = f;
    unsigned r = v.u + 0x7FFF + ((v.u >> 16) & 1);
    return (u16)(r >> 16);
}
__device__ __forceinline__ u16 f2h(float f) {
    f16 h = (f16)f;
    union { f16 h; u16 u; } v; v.h = h;
    return v.u;
}
__device__ __forceinline__ unsigned char f2e4m3(float f) {
    int p;
    asm volatile("v_cvt_pk_fp8_f32 %0, %1, %2" : "=v"(p) : "v"(f), "v"(f));
    return (unsigned char)(p & 0xff);
}
__device__ __forceinline__ float sigm(float x) { return 1.f / (1.f + __expf(-x)); }
__device__ __forceinline__ float fast_tanh(float x) {
    float ax = fabsf(x);
    float e = __expf(2.f * ax);
    float r = 1.f - 2.f / (e + 1.f);   // overflow-safe: e=inf -> r=1
    return copysignf(r, x);
}

// Inline-asm MFMA with explicit operand classes (gfx950: A/B may be AGPR).
// Chains only reuse D as SrcC (0 wait states required). Volatile: source
// order IS the issue order (8 independent chains per cg-pair -> no bubbles).
#define MFMA_INIT(D, A, B, C) \
    asm volatile("v_mfma_f32_16x16x32_f16 %0, %1, %2, %3" \
                 : "=v"(D) : "v"(A), "a"(B), "v"(C))
#define MFMA_AG(D, A, B) \
    asm volatile("v_mfma_f32_16x16x32_f16 %0, %1, %2, %0" \
                 : "+v"(D) : "v"(A), "a"(B))
#define MFMA_F8(D, A, B) \
    asm volatile("v_mfma_f32_16x16x32_fp8_fp8 %0, %1, %2, %0" \
                 : "+v"(D) : "v"(A), "v"(B))

// ---------------------------------------------------------------------------
// Weight prep: transposes to [N][K] bf16 for MFMA B-operand for the GEMMs,
// and packs Ul for the LSTM in TWO dtypes (full register residency):
//   f16 frags (k 0..127, AGPR): F = (w*16+cg*4+g)*4 + kt, kt in [0,4)
//     lane l holds 8 f16: k = kt*32 + (l>>4)*8 + j, n = g*256+w*64+cg*16+(l&15)
//   fp8 e4m3 frags (k 128..255, VGPR): same tile order, kt8 in [0,4),
//     lane l holds 8 bytes: k = 128 + kt8*32 + (l>>4)*8 + j
//   Both operands of each MFMA use the same lane->k mapping, so the result
//   is invariant to the exact HW k-permutation.
// ---------------------------------------------------------------------------
__global__ __launch_bounds__(256) void prep_kernel(
    const float* __restrict__ Wx, const float* __restrict__ Wc,
    const float* __restrict__ Wl, const float* __restrict__ Wo,
    const float* __restrict__ Ul,
    u16* __restrict__ wxT, u16* __restrict__ wcT, u16* __restrict__ wlT,
    u16* __restrict__ woT, u16* __restrict__ ulB)
{
    int i = blockIdx.x * 256 + threadIdx.x;
    if (i < 65536) {                    // WxT[n][k] : 128x512
        int n = i >> 9, k = i & 511;
        wxT[i] = f2bf(Wx[k * 128 + n]);
    } else if (i < 131072) {            // WcT
        int t = i - 65536;
        int n = t >> 9, k = t & 511;
        wcT[t] = f2bf(Wc[k * 128 + n]);
    } else if (i < 425984) {            // WlT[n][k] : 1024x288 (K padded 257->288)
        int t = i - 131072;
        int n = t / 288, k = t % 288;
        wlT[t] = (k < 257) ? f2bf(Wl[k * 1024 + n]) : (u16)0;
    } else if (i < 491520) {            // WoT[n][k] : 256x256
        int t = i - 425984;
        int n = t >> 8, k = t & 255;
        woT[t] = f2bf(Wo[k * 256 + n]);
    } else {                            // ulB, i in [491520, 524288)
        int e = i - 491520;             // [0, 32768)
        if (e < 16384) {                // f16 frags (k 0..127)
            int F = e >> 6, lane = e & 63;
            int m16 = lane & 15, quad = lane >> 4;
            int tile = F >> 2, kt = F & 3;
            int w = tile >> 4, cg = (tile >> 2) & 3, g = tile & 3;
            int n = g * 256 + w * 64 + cg * 16 + m16;
            int k0 = kt * 32 + quad * 8;
            u16* o = ulB + (size_t)e * 8;
            #pragma unroll
            for (int jj = 0; jj < 8; ++jj)
                o[jj] = f2h(Ul[(size_t)(k0 + jj) * 1024 + n]);
        } else {                        // fp8 frags (k 128..255)
            int e2 = e - 16384;
            int F = e2 >> 6, lane = e2 & 63;
            int m16 = lane & 15, quad = lane >> 4;
            int tile = F >> 2, kt8 = F & 3;
            int w = tile >> 4, cg = (tile >> 2) & 3, g = tile & 3;
            int n = g * 256 + w * 64 + cg * 16 + m16;
            int k0 = 128 + kt8 * 32 + quad * 8;
            unsigned char* o = (unsigned char*)ulB + 262144 + (size_t)e2 * 8;
            #pragma unroll
            for (int jj = 0; jj < 8; ++jj)
                o[jj] = f2e4m3(Ul[(size_t)(k0 + jj) * 1024 + n]);
        }
    }
}

// ---------------------------------------------------------------------------
// s[b,t] = sum_k x[b,t,k]   (one wave per row)
// ---------------------------------------------------------------------------
__global__ __launch_bounds__(256) void row_sums(const float4* __restrict__ x4,
                                                float* __restrict__ s)
{
    int w = threadIdx.x >> 6, lane = threadIdx.x & 63;
    size_t row = (size_t)blockIdx.x * 4 + w;
    const float4* r = x4 + row * 128;
    float4 a = r[lane], b = r[64 + lane];
    float sum = a.x + a.y + a.z + a.w + b.x + b.y + b.z + b.w;
    #pragma unroll
    for (int d = 32; d >= 1; d >>= 1) sum += __shfl_xor(sum, d);
    if (lane == 0) s[row] = sum;
}

// ---------------------------------------------------------------------------
// Count recurrence, 3-phase chunked (8 chunks of 128 steps per batch).
// ---------------------------------------------------------------------------
__global__ __launch_bounds__(512) void count_phaseA(const float* __restrict__ x,
                                                    const float* __restrict__ s,
                                                    float* __restrict__ cend,
                                                    float* __restrict__ Pq)
{
    int k = threadIdx.x, bi = blockIdx.x;
    int b = bi >> 3, qc = bi & 7;
    const float* xb = x + ((size_t)b * 1024 + qc * 128) * 512;
    const float* sb = s + b * 1024 + qc * 128;
    float c = 0.f, P = 1.f;
    for (int t0 = 0; t0 < 128; t0 += 8) {
        float xv[8], sv[8];
        #pragma unroll
        for (int i = 0; i < 8; ++i) {
            xv[i] = xb[(size_t)(t0 + i) * 512 + k];
            sv[i] = sb[t0 + i];
        }
        #pragma unroll
        for (int i = 0; i < 8; ++i) { c = sv[i] * c + xv[i]; P *= sv[i]; }
    }
    cend[(size_t)bi * 512 + k] = c;
    if (k == 0) Pq[bi] = P;
}

__global__ __launch_bounds__(512) void count_phaseB(const float* __restrict__ cend,
                                                    const float* __restrict__ Pq,
                                                    float* __restrict__ cin)
{
    int k = threadIdx.x, b = blockIdx.x;
    float c = 0.f;
    for (int q = 0; q < 8; ++q) {
        int bi = b * 8 + q;
        cin[(size_t)bi * 512 + k] = c;
        c = Pq[bi] * c + cend[(size_t)bi * 512 + k];
    }
}

__global__ __launch_bounds__(512) void count_phaseC(const float* __restrict__ x,
                                                    const float* __restrict__ s,
                                                    const float* __restrict__ cin,
                                                    u16* __restrict__ xbf,
                                                    u16* __restrict__ clog)
{
    int k = threadIdx.x, bi = blockIdx.x;
    int b = bi >> 3, qc = bi & 7;
    size_t base = ((size_t)b * 1024 + qc * 128) * 512;
    const float* xb = x + base;
    const float* sb = s + b * 1024 + qc * 128;
    u16* xo = xbf + base;
    u16* co = clog + base;
    float c = cin[(size_t)bi * 512 + k];
    for (int t0 = 0; t0 < 128; t0 += 8) {
        float xv[8], sv[8];
        #pragma unroll
        for (int i = 0; i < 8; ++i) {
            xv[i] = xb[(size_t)(t0 + i) * 512 + k];
            sv[i] = sb[t0 + i];
        }
        #pragma unroll
        for (int i = 0; i < 8; ++i) {
            c = sv[i] * c + xv[i];
            size_t idx = (size_t)(t0 + i) * 512 + k;
            xo[idx] = f2bf(xv[i]);
            co[idx] = f2bf(log1pf(c));
        }
    }
}

// ---------------------------------------------------------------------------
// xc[:,256] = exp(-(delta*Wd+bd)); xc[:,257:288] = 0
// ---------------------------------------------------------------------------
__global__ __launch_bounds__(256) void fill_xc(const float* __restrict__ delta,
                                               const float* __restrict__ Wd,
                                               const float* __restrict__ bd,
                                               u16* __restrict__ xc)
{
    int i = blockIdx.x * 256 + threadIdx.x;   // 65536*32
    int row = i >> 5, cc = i & 31;
    float v = 0.f;
    if (cc == 0) v = __expf(-(delta[row] * Wd[0] + bd[0]));
    xc[(size_t)row * 288 + 256 + cc] = f2bf(v);
}

// ---------------------------------------------------------------------------
// Generic 128x128-tile bf16 MFMA GEMM: C[row, colofs+col] = A@B + bias.
// ---------------------------------------------------------------------------
template <int EPI>
__global__ __launch_bounds__(256) void gemm128(const u16* __restrict__ A,
                                               const u16* __restrict__ BT,
                                               const float* __restrict__ bias,
                                               u16* __restrict__ C,
                                               int K, int ldc, int colofs)
{
    __shared__ u16 Alds[128 * 40];
    __shared__ u16 Blds[128 * 40];
    int tid = threadIdx.x;
    int m0 = blockIdx.x * 128, n0 = blockIdx.y * 128;
    int lane = tid & 63, w = tid >> 6, quad = lane >> 4, m16 = lane & 15;
    int wm = w & 1, wn = w >> 1;
    f4v acc[4][4];
    #pragma unroll
    for (int i = 0; i < 4; ++i)
        #pragma unroll
        for (int j = 0; j < 4; ++j) acc[i][j] = (f4v){0.f, 0.f, 0.f, 0.f};

    for (int k0 = 0; k0 < K; k0 += 32) {
        #pragma unroll
        for (int p = 0; p < 2; ++p) {
            int e = (p * 256 + tid) * 8;
            int r = e >> 5, cc = e & 31;
            *(uint4*)&Alds[r * 40 + cc] =
                *(const uint4*)&A[(size_t)(m0 + r) * K + k0 + cc];
            *(uint4*)&Blds[r * 40 + cc] =
                *(const uint4*)&BT[(size_t)(n0 + r) * K + k0 + cc];
        }
        __syncthreads();
        s8v af[4], bf[4];
        #pragma unroll
        for (int i = 0; i < 4; ++i)
            af[i] = *(const s8v*)&Alds[(wm * 64 + i * 16 + m16) * 40 + quad * 8];
        #pragma unroll
        for (int i = 0; i < 4; ++i)
            bf[i] = *(const s8v*)&Blds[(wn * 64 + i * 16 + m16) * 40 + quad * 8];
        #pragma unroll
        for (int i = 0; i < 4; ++i)
            #pragma unroll
            for (int nj = 0; nj < 4; ++nj)
                acc[i][nj] = __builtin_amdgcn_mfma_f32_16x16x32_bf16(
                    af[i], bf[nj], acc[i][nj], 0, 0, 0);
        __syncthreads();
    }
    #pragma unroll
    for (int nj = 0; nj < 4; ++nj) {
        int col = n0 + wn * 64 + nj * 16 + m16;
        float bv = bias[col];
        #pragma unroll
        for (int i = 0; i < 4; ++i)
            #pragma unroll
            for (int r = 0; r < 4; ++r) {
                int row = m0 + wm * 64 + i * 16 + quad * 4 + r;
                float v = acc[i][nj][r] + bv;
                C[(size_t)row * ldc + colofs + col] = (EPI == 0) ? f2bf(v) : f2h(v);
            }
    }
}

// ---------------------------------------------------------------------------
// LSTM over T=1024 via broadcast-A MFMA GEMV. One block per batch, 256 thr
// (4 waves, 1/SIMD, 512-reg budget). Wave w owns h-cols [w*64, w*64+64).
// FULL register residency of Ul (mixed precision):
//   k 0..127   -> 64 f16 frags pinned in AGPRs (exactly 256)
//   k 128..255 -> 64 fp8 e4m3 frags in VGPRs (128 regs) via
//                 v_mfma_f32_16x16x32_fp8_fp8 into the same f32 chains.
// ZERO per-step weight traffic. LDS carries only h: dual-format state
// (cols<128 f16 / cols>=128 fp8, wave-uniform store split), 12 broadcast
// reads per wave per step. cg-pairs are interleaved (8 independent MFMA
// chains) so the 128 MFMAs run issue-bound (~620 cy). Per-step barrier:
// s_waitcnt lgkmcnt(0) + s_barrier only (vmem stays in flight).
// ---------------------------------------------------------------------------
#define PAIR_BODY(CGA, CGB)                                            \
    {                                                                  \
        f4v A0, A1, A2, A3, B0, B1, B2, B3;                            \
        MFMA_INIT(A0, av[0], wa[CGA][0][0], z4);                       \
        MFMA_INIT(A1, av[0], wa[CGA][1][0], z4);                       \
        MFMA_INIT(A2, av[0], wa[CGA][2][0], z4);                       \
        MFMA_INIT(A3, av[0], wa[CGA][3][0], z4);                       \
        MFMA_INIT(B0, av[0], wa[CGB][0][0], z4);                       \
        MFMA_INIT(B1, av[0], wa[CGB][1][0], z4);                       \
        MFMA_INIT(B2, av[0], wa[CGB][2][0], z4);                       \
        MFMA_INIT(B3, av[0], wa[CGB][3][0], z4);                       \
        _Pragma("unroll")                                              \
        for (int kt = 1; kt < 4; ++kt) {                               \
            MFMA_AG(A0, av[kt], wa[CGA][0][kt]);                       \
            MFMA_AG(A1, av[kt], wa[CGA][1][kt]);                       \
            MFMA_AG(A2, av[kt], wa[CGA][2][kt]);                       \
            MFMA_AG(A3, av[kt], wa[CGA][3][kt]);                       \
            MFMA_AG(B0, av[kt], wa[CGB][0][kt]);                       \
            MFMA_AG(B1, av[kt], wa[CGB][1][kt]);                       \
            MFMA_AG(B2, av[kt], wa[CGB][2][kt]);                       \
            MFMA_AG(B3, av[kt], wa[CGB][3][kt]);                       \
        }                                                              \
        _Pragma("unroll")                                              \
        for (int k8 = 0; k8 < 4; ++k8) {                               \
            MFMA_F8(A0, av8[k8], wf8[CGA][0][k8]);                     \
            MFMA_F8(A1, av8[k8], wf8[CGA][1][k8]);                     \
            MFMA_F8(A2, av8[k8], wf8[CGA][2][k8]);                     \
            MFMA_F8(A3, av8[k8], wf8[CGA][3][k8]);                     \
            MFMA_F8(B0, av8[k8], wf8[CGB][0][k8]);                     \
            MFMA_F8(B1, av8[k8], wf8[CGB][1][k8]);                     \
            MFMA_F8(B2, av8[k8], wf8[CGB][2][k8]);                     \
            MFMA_F8(B3, av8[k8], wf8[CGB][3][k8]);                     \
        }                                                              \
        asm volatile("s_nop 7\n\ts_nop 7");                            \
        zq0 = (quad == CGA) ? A0[0] : ((quad == CGB) ? B0[0] : zq0);   \
        zq1 = (quad == CGA) ? A1[0] : ((quad == CGB) ? B1[0] : zq1);   \
        zq2 = (quad == CGA) ? A2[0] : ((quad == CGB) ? B2[0] : zq2);   \
        zq3 = (quad == CGA) ? A3[0] : ((quad == CGB) ? B3[0] : zq3);   \
    }

__global__ __launch_bounds__(256, 1) void lstm_kernel(const f16* __restrict__ pre,
                                                      const u16* __restrict__ ulB,
                                                      u16* __restrict__ hout)
{
    __shared__ f16 hl[2][128];                       // h cols 0..127 (f16)
    __shared__ __align__(8) unsigned char hl8[2][128]; // h cols 128..255 (fp8)
    const int tid = threadIdx.x, b = blockIdx.x;
    const int w = tid >> 6, lane = tid & 63, quad = lane >> 4;

    const f16x8* ub16 = (const f16x8*)ulB;
    const i64* ub8 = (const i64*)((const char*)ulB + 262144);
    // f16 weights k 0..127 pinned in AGPRs (64 frags = 256 AGPRs)
    f16x8 wa[4][4][4];
    #pragma unroll
    for (int cg = 0; cg < 4; ++cg)
        #pragma unroll
        for (int g = 0; g < 4; ++g)
            #pragma unroll
            for (int kt = 0; kt < 4; ++kt) {
                f16x8 tmp = ub16[(size_t)(((w * 16 + cg * 4 + g) * 4 + kt) * 64 + lane)];
                asm("" : "=a"(wa[cg][g][kt]) : "0"(tmp));
            }
    // fp8 weights k 128..255 in VGPRs (64 frags = 128 VGPRs)
    i64 wf8[4][4][4];
    #pragma unroll
    for (int cg = 0; cg < 4; ++cg)
        #pragma unroll
        for (int g = 0; g < 4; ++g)
            #pragma unroll
            for (int k8 = 0; k8 < 4; ++k8)
                wf8[cg][g][k8] =
                    ub8[(size_t)(((w * 16 + cg * 4 + g) * 4 + k8) * 64 + lane)];

    const f16* prep_ = pre + (size_t)b * 1024 * 1024;
    const f16* pcol = prep_ + tid;          // lane's column stream (col = tid)
    u16* ho = hout + (size_t)b * 1024 * 256;
    if (tid < 128) hl[0][tid] = (f16)0.f;
    else hl8[0][tid - 128] = 0;             // fp8 zero
    float c = 0.f;
    f16 pcur[4];
    #pragma unroll
    for (int g = 0; g < 4; ++g) pcur[g] = pcol[g * 256];
    f4v z4 = {0.f, 0.f, 0.f, 0.f};
    __syncthreads();

    #pragma unroll 1
    for (int t = 0; t < 1024; ++t) {
        const int cur = t & 1;
        // h k-slices (broadcast LDS reads): f16 for k<128, fp8 for k>=128
        f16x8 av[4];
        #pragma unroll
        for (int kt = 0; kt < 4; ++kt)
            av[kt] = *(const f16x8*)&hl[cur][kt * 32 + quad * 8];
        i64 av8[4];
        #pragma unroll
        for (int k8 = 0; k8 < 4; ++k8)
            av8[k8] = *(const i64*)&hl8[cur][k8 * 32 + quad * 8];
        // prefetch pre[t+1] (stays in flight across the barrier)
        int t1 = (t < 1023) ? (t + 1) : 1023;
        f16 pnext[4];
        #pragma unroll
        for (int g = 0; g < 4; ++g) pnext[g] = pcol[(size_t)t1 * 1024 + g * 256];

        float zq0 = 0.f, zq1 = 0.f, zq2 = 0.f, zq3 = 0.f;
        PAIR_BODY(0, 1);
        PAIR_BODY(2, 3);

        // gates, once per lane (column = tid; cg == quad selected above)
        float z0 = zq0 + (float)pcur[0];
        float z1 = zq1 + (float)pcur[1];
        float z2 = zq2 + (float)pcur[2];
        float z3 = zq3 + (float)pcur[3];
        float ig = sigm(z0), fg = sigm(z1);
        float gg = fast_tanh(z2), og = sigm(z3);
        c = fg * c + ig * gg;
        float hs = og * fast_tanh(c);
        if (w < 2) hl[cur ^ 1][tid] = (f16)hs;            // cols 0..127
        else hl8[cur ^ 1][tid - 128] = f2e4m3(hs);        // cols 128..255
        ho[(size_t)t * 256 + tid] = f2bf(hs);             // fire-and-forget
        #pragma unroll
        for (int g = 0; g < 4; ++g) pcur[g] = pnext[g];
        // raw barrier: drain LDS only; vmem ops continue across
        asm volatile("s_waitcnt lgkmcnt(0)\n\ts_barrier" ::: "memory");
    }
}

// ---------------------------------------------------------------------------
// out[row] = sum_n sigmoid(h[row]@Wo[:,n] + bo[n]) * q[row,n]
// ---------------------------------------------------------------------------
__global__ __launch_bounds__(256) void gemm_out(const u16* __restrict__ H,
                                                const u16* __restrict__ woT,
                                                const float* __restrict__ bo,
                                                const float* __restrict__ q,
                                                float* __restrict__ out)
{
    __shared__ u16 Alds[64 * 40];
    __shared__ u16 Blds[256 * 40];
    __shared__ float red[64][4];
    int tid = threadIdx.x;
    int m0 = blockIdx.x * 64;
    int lane = tid & 63, w = tid >> 6, quad = lane >> 4, m16 = lane & 15;
    f4v acc[4][4];
    #pragma unroll
    for (int i = 0; i < 4; ++i)
        #pragma unroll
        for (int j = 0; j < 4; ++j) acc[i][j] = (f4v){0.f, 0.f, 0.f, 0.f};

    for (int k0 = 0; k0 < 256; k0 += 32) {
        {
            int e = tid * 8;
            int r = e >> 5, cc = e & 31;
            *(uint4*)&Alds[r * 40 + cc] =
                *(const uint4*)&H[(size_t)(m0 + r) * 256 + k0 + cc];
        }
        #pragma unroll
        for (int p = 0; p < 4; ++p) {
            int e = (p * 256 + tid) * 8;
            int r = e >> 5, cc = e & 31;
            *(uint4*)&Blds[r * 40 + cc] =
                *(const uint4*)&woT[(size_t)r * 256 + k0 + cc];
        }
        __syncthreads();
        s8v af[4], bf[4];
        #pragma unroll
        for (int i = 0; i < 4; ++i)
            af[i] = *(const s8v*)&Alds[(i * 16 + m16) * 40 + quad * 8];
        #pragma unroll
        for (int i = 0; i < 4; ++i)
            bf[i] = *(const s8v*)&Blds[(w * 64 + i * 16 + m16) * 40 + quad * 8];
        #pragma unroll
        for (int i = 0; i < 4; ++i)
            #pragma unroll
            for (int nj = 0; nj < 4; ++nj)
                acc[i][nj] = __builtin_amdgcn_mfma_f32_16x16x32_bf16(
                    af[i], bf[nj], acc[i][nj], 0, 0, 0);
        __syncthreads();
    }
    float rsum[4][4];
    #pragma unroll
    for (int i = 0; i < 4; ++i)
        #pragma unroll
        for (int r = 0; r < 4; ++r) rsum[i][r] = 0.f;
    #pragma unroll
    for (int nj = 0; nj < 4; ++nj) {
        int col = w * 64 + nj * 16 + m16;
        float bv = bo[col];
        #pragma unroll
        for (int i = 0; i < 4; ++i)
            #pragma unroll
            for (int r = 0; r < 4; ++r) {
                int row = m0 + i * 16 + quad * 4 + r;
                float v = sigm(acc[i][nj][r] + bv);
                rsum[i][r] += v * q[(size_t)row * 256 + col];
            }
    }
    #pragma unroll
    for (int d = 1; d <= 8; d <<= 1)
        #pragma unroll
        for (int i = 0; i < 4; ++i)
            #pragma unroll
            for (int r = 0; r < 4; ++r) rsum[i][r] += __shfl_xor(rsum[i][r], d);
    if (m16 == 0) {
        #pragma unroll
        for (int i = 0; i < 4; ++i)
            #pragma unroll
            for (int r = 0; r < 4; ++r)
                red[i * 16 + quad * 4 + r][w] = rsum[i][r];
    }
    __syncthreads();
    if (tid < 64)
        out[m0 + tid] = red[tid][0] + red[tid][1] + red[tid][2] + red[tid][3];
}

// ---------------------------------------------------------------------------
extern "C" void kernel_launch(void* const* d_in, const int* in_sizes, int n_in,
                              void* d_out, int out_size, void* d_ws, size_t ws_size,
                              hipStream_t stream)
{
    (void)in_sizes; (void)n_in; (void)out_size; (void)ws_size;
    const float* x     = (const float*)d_in[0];
    const float* delta = (const float*)d_in[1];
    const float* q     = (const float*)d_in[2];
    const float* Wx    = (const float*)d_in[3];
    const float* bx    = (const float*)d_in[4];
    const float* Wc    = (const float*)d_in[5];
    const float* bc    = (const float*)d_in[6];
    const float* Wd    = (const float*)d_in[7];
    const float* bd    = (const float*)d_in[8];
    const float* Wl    = (const float*)d_in[9];
    const float* Ul    = (const float*)d_in[10];
    const float* bl    = (const float*)d_in[11];
    const float* Wo    = (const float*)d_in[12];
    const float* bo    = (const float*)d_in[13];

    char* ws = (char*)d_ws;
    float* s_buf = (float*)(ws + 0);            // 256 KB
    u16* ulB     = (u16*)(ws + 262144);         // 384 KB (f16 256K + fp8 128K)
    u16* wxT     = (u16*)(ws + 786432);         // 128 KB
    u16* wcT     = (u16*)(ws + 917504);         // 128 KB
    u16* wlT     = (u16*)(ws + 1048576);        // 576 KB
    u16* woT     = (u16*)(ws + 1638400);        // 128 KB
    u16* xc      = (u16*)(ws + 1769472);        // 36 MB  [65536 x 288] bf16
    u16* hbuf    = (u16*)(ws + 39518208);       // 32 MB  [65536 x 256] bf16
    u16* xbf     = (u16*)(ws + 73072640);       // 64 MB  bf16 copy of x
    u16* clog    = (u16*)(ws + 140181504);      // 64 MB  log1p(counts) bf16
    f16* pre     = (f16*)(ws + 73072640);       // 128 MB f16, aliases xbf+clog
    // count-scan scratch lives in the (not yet used) hbuf region
    float* cend  = (float*)hbuf;                // 1 MB
    float* cin   = (float*)(ws + 39518208 + (1 << 20));   // 1 MB
    float* Pq    = (float*)(ws + 39518208 + (2 << 20));   // 2 KB

    prep_kernel<<<2048, 256, 0, stream>>>(Wx, Wc, Wl, Wo, Ul, wxT, wcT, wlT, woT, ulB);
    row_sums<<<16384, 256, 0, stream>>>((const float4*)x, s_buf);
    count_phaseA<<<512, 512, 0, stream>>>(x, s_buf, cend, Pq);
    count_phaseB<<<64, 512, 0, stream>>>(cend, Pq, cin);
    count_phaseC<<<512, 512, 0, stream>>>(x, s_buf, cin, xbf, clog);
    fill_xc<<<8192, 256, 0, stream>>>(delta, Wd, bd, xc);
    gemm128<0><<<dim3(512, 1), 256, 0, stream>>>(xbf, wxT, bx, xc, 512, 288, 0);
    gemm128<0><<<dim3(512, 1), 256, 0, stream>>>(clog, wcT, bc, xc, 512, 288, 128);
    gemm128<1><<<dim3(512, 8), 256, 0, stream>>>(xc, wlT, bl, (u16*)pre, 288, 1024, 0);
    lstm_kernel<<<64, 256, 0, stream>>>(pre, ulB, hbuf);
    gemm_out<<<1024, 256, 0, stream>>>(hbuf, woT, bo, q, (float*)d_out);
}

// Round 9
// 1414.440 us; speedup vs baseline: 4.5434x; 1.3204x over previous
//
#include <hip/hip_runtime.h>
#include <hip/hip_bf16.h>

typedef unsigned short u16;
typedef _Float16 f16;
typedef _Float16 f16x8 __attribute__((ext_vector_type(8)));
typedef short s8v __attribute__((ext_vector_type(8)));
typedef float f4v __attribute__((ext_vector_type(4)));
typedef int i4v __attribute__((ext_vector_type(4)));

__device__ __forceinline__ u16 f2bf(float f) {
    union { float f; unsigned u; } v; v.f = f;
    unsigned r = v.u + 0x7FFF + ((v.u >> 16) & 1);
    return (u16)(r >> 16);
}
__device__ __forceinline__ u16 f2h(float f) {
    f16 h = (f16)f;
    union { f16 h; u16 u; } v; v.h = h;
    return v.u;
}
__device__ __forceinline__ float sigm(float x) { return 1.f / (1.f + __expf(-x)); }
__device__ __forceinline__ float fast_tanh(float x) {
    float ax = fabsf(x);
    float e = __expf(2.f * ax);
    float r = 1.f - 2.f / (e + 1.f);   // overflow-safe: e=inf -> r=1
    return copysignf(r, x);
}

// Inline-asm i8 MFMA (K=64: 2x K/instr vs f16 K=32 at same issue cost).
// A from VGPR (broadcast h), B from AGPR (resident weights), i32 acc.
// INIT uses EARLY-CLOBBER "=&v": MFMA D must never overlap A/B (HW hazard);
// without "&" the allocator may place D over a dying A input.
#define MFMA_I8_INIT(D, A, B, C) \
    asm volatile("v_mfma_i32_16x16x64_i8 %0, %1, %2, %3" \
                 : "=&v"(D) : "v"(A), "a"(B), "v"(C))
#define MFMA_I8(D, A, B) \
    asm volatile("v_mfma_i32_16x16x64_i8 %0, %1, %2, %0" \
                 : "+v"(D) : "v"(A), "a"(B))

// ---------------------------------------------------------------------------
// Per-column |Ul| max -> quant scale (prep input) and dequant const (lstm).
// ---------------------------------------------------------------------------
__global__ __launch_bounds__(256) void colmax(const float* __restrict__ Ul,
                                              float* __restrict__ cm,
                                              float* __restrict__ dq)
{
    int n = blockIdx.x * 256 + threadIdx.x;   // [0,1024)
    float m = 0.f;
    for (int k = 0; k < 256; ++k) m = fmaxf(m, fabsf(Ul[(size_t)k * 1024 + n]));
    m = fmaxf(m, 1e-8f);
    cm[n] = m;
    dq[n] = m / 16129.0f;                     // m / (127*127)
}

// ---------------------------------------------------------------------------
// Weight prep: transposes to [N][K] bf16 for MFMA B-operand for the GEMMs,
// and packs Ul as i8 MFMA B-frags (16x16x64) with per-column scale 127/cm[n]:
//   256 frags, F = (w*16 + cg*4 + g)*4 + kt  (w wave, cg col-cluster, g gate,
//   kt k-slot of 64); lane l holds 16 bytes:
//     k = kt*64 + (l>>4)*16 + j (j 0..15),  n = g*256 + w*64 + cg*16 + (l&15)
//   A (h) and B use the same lane->k mapping, so any HW k-permutation
//   cancels; per-column dequant applied after accumulation.
// ---------------------------------------------------------------------------
__global__ __launch_bounds__(256) void prep_kernel(
    const float* __restrict__ Wx, const float* __restrict__ Wc,
    const float* __restrict__ Wl, const float* __restrict__ Wo,
    const float* __restrict__ Ul, const float* __restrict__ cm,
    u16* __restrict__ wxT, u16* __restrict__ wcT, u16* __restrict__ wlT,
    u16* __restrict__ woT, u16* __restrict__ ulB)
{
    int i = blockIdx.x * 256 + threadIdx.x;
    if (i < 65536) {                    // WxT[n][k] : 128x512
        int n = i >> 9, k = i & 511;
        wxT[i] = f2bf(Wx[k * 128 + n]);
    } else if (i < 131072) {            // WcT
        int t = i - 65536;
        int n = t >> 9, k = t & 511;
        wcT[t] = f2bf(Wc[k * 128 + n]);
    } else if (i < 425984) {            // WlT[n][k] : 1024x288 (K padded 257->288)
        int t = i - 131072;
        int n = t / 288, k = t % 288;
        wlT[t] = (k < 257) ? f2bf(Wl[k * 1024 + n]) : (u16)0;
    } else if (i < 491520) {            // WoT[n][k] : 256x256
        int t = i - 425984;
        int n = t >> 8, k = t & 255;
        woT[t] = f2bf(Wo[k * 256 + n]);
    } else {                            // ulB i8 frags, i in [491520, 524288)
        int e = i - 491520;             // [0, 32768): 8 bytes each
        int fg = e >> 7, rem = e & 127;
        int lane = rem >> 1, hf = rem & 1;
        int w = fg >> 6, t2 = fg & 63, tile = t2 >> 2, kt = t2 & 3;
        int cg = tile >> 2, g = tile & 3;
        int m16 = lane & 15, quad = lane >> 4;
        int n = g * 256 + w * 64 + cg * 16 + m16;
        int kb = kt * 64 + quad * 16 + hf * 8;
        float sw = 127.0f / cm[n];
        char* o = (char*)ulB + ((size_t)(fg * 64 + lane) * 16 + hf * 8);
        #pragma unroll
        for (int jj = 0; jj < 8; ++jj) {
            float v = Ul[(size_t)(kb + jj) * 1024 + n] * sw;
            int bq = (int)rintf(v);
            bq = bq > 127 ? 127 : (bq < -127 ? -127 : bq);
            o[jj] = (char)bq;
        }
    }
}

// ---------------------------------------------------------------------------
// s[b,t] = sum_k x[b,t,k]   (one wave per row)
// ---------------------------------------------------------------------------
__global__ __launch_bounds__(256) void row_sums(const float4* __restrict__ x4,
                                                float* __restrict__ s)
{
    int w = threadIdx.x >> 6, lane = threadIdx.x & 63;
    size_t row = (size_t)blockIdx.x * 4 + w;
    const float4* r = x4 + row * 128;
    float4 a = r[lane], b = r[64 + lane];
    float sum = a.x + a.y + a.z + a.w + b.x + b.y + b.z + b.w;
    #pragma unroll
    for (int d = 32; d >= 1; d >>= 1) sum += __shfl_xor(sum, d);
    if (lane == 0) s[row] = sum;
}

// ---------------------------------------------------------------------------
// Count recurrence, 3-phase chunked (8 chunks of 128 steps per batch).
// ---------------------------------------------------------------------------
__global__ __launch_bounds__(512) void count_phaseA(const float* __restrict__ x,
                                                    const float* __restrict__ s,
                                                    float* __restrict__ cend,
                                                    float* __restrict__ Pq)
{
    int k = threadIdx.x, bi = blockIdx.x;
    int b = bi >> 3, qc = bi & 7;
    const float* xb = x + ((size_t)b * 1024 + qc * 128) * 512;
    const float* sb = s + b * 1024 + qc * 128;
    float c = 0.f, P = 1.f;
    for (int t0 = 0; t0 < 128; t0 += 8) {
        float xv[8], sv[8];
        #pragma unroll
        for (int i = 0; i < 8; ++i) {
            xv[i] = xb[(size_t)(t0 + i) * 512 + k];
            sv[i] = sb[t0 + i];
        }
        #pragma unroll
        for (int i = 0; i < 8; ++i) { c = sv[i] * c + xv[i]; P *= sv[i]; }
    }
    cend[(size_t)bi * 512 + k] = c;
    if (k == 0) Pq[bi] = P;
}

__global__ __launch_bounds__(512) void count_phaseB(const float* __restrict__ cend,
                                                    const float* __restrict__ Pq,
                                                    float* __restrict__ cin)
{
    int k = threadIdx.x, b = blockIdx.x;
    float c = 0.f;
    for (int q = 0; q < 8; ++q) {
        int bi = b * 8 + q;
        cin[(size_t)bi * 512 + k] = c;
        c = Pq[bi] * c + cend[(size_t)bi * 512 + k];
    }
}

__global__ __launch_bounds__(512) void count_phaseC(const float* __restrict__ x,
                                                    const float* __restrict__ s,
                                                    const float* __restrict__ cin,
                                                    u16* __restrict__ xbf,
                                                    u16* __restrict__ clog)
{
    int k = threadIdx.x, bi = blockIdx.x;
    int b = bi >> 3, qc = bi & 7;
    size_t base = ((size_t)b * 1024 + qc * 128) * 512;
    const float* xb = x + base;
    const float* sb = s + b * 1024 + qc * 128;
    u16* xo = xbf + base;
    u16* co = clog + base;
    float c = cin[(size_t)bi * 512 + k];
    for (int t0 = 0; t0 < 128; t0 += 8) {
        float xv[8], sv[8];
        #pragma unroll
        for (int i = 0; i < 8; ++i) {
            xv[i] = xb[(size_t)(t0 + i) * 512 + k];
            sv[i] = sb[t0 + i];
        }
        #pragma unroll
        for (int i = 0; i < 8; ++i) {
            c = sv[i] * c + xv[i];
            size_t idx = (size_t)(t0 + i) * 512 + k;
            xo[idx] = f2bf(xv[i]);
            co[idx] = f2bf(log1pf(c));
        }
    }
}

// ---------------------------------------------------------------------------
// xc[:,256] = exp(-(delta*Wd+bd)); xc[:,257:288] = 0
// ---------------------------------------------------------------------------
__global__ __launch_bounds__(256) void fill_xc(const float* __restrict__ delta,
                                               const float* __restrict__ Wd,
                                               const float* __restrict__ bd,
                                               u16* __restrict__ xc)
{
    int i = blockIdx.x * 256 + threadIdx.x;   // 65536*32
    int row = i >> 5, cc = i & 31;
    float v = 0.f;
    if (cc == 0) v = __expf(-(delta[row] * Wd[0] + bd[0]));
    xc[(size_t)row * 288 + 256 + cc] = f2bf(v);
}

// ---------------------------------------------------------------------------
// Generic 128x128-tile bf16 MFMA GEMM: C[row, colofs+col] = A@B + bias.
// ---------------------------------------------------------------------------
template <int EPI>
__global__ __launch_bounds__(256) void gemm128(const u16* __restrict__ A,
                                               const u16* __restrict__ BT,
                                               const float* __restrict__ bias,
                                               u16* __restrict__ C,
                                               int K, int ldc, int colofs)
{
    __shared__ u16 Alds[128 * 40];
    __shared__ u16 Blds[128 * 40];
    int tid = threadIdx.x;
    int m0 = blockIdx.x * 128, n0 = blockIdx.y * 128;
    int lane = tid & 63, w = tid >> 6, quad = lane >> 4, m16 = lane & 15;
    int wm = w & 1, wn = w >> 1;
    f4v acc[4][4];
    #pragma unroll
    for (int i = 0; i < 4; ++i)
        #pragma unroll
        for (int j = 0; j < 4; ++j) acc[i][j] = (f4v){0.f, 0.f, 0.f, 0.f};

    for (int k0 = 0; k0 < K; k0 += 32) {
        #pragma unroll
        for (int p = 0; p < 2; ++p) {
            int e = (p * 256 + tid) * 8;
            int r = e >> 5, cc = e & 31;
            *(uint4*)&Alds[r * 40 + cc] =
                *(const uint4*)&A[(size_t)(m0 + r) * K + k0 + cc];
            *(uint4*)&Blds[r * 40 + cc] =
                *(const uint4*)&BT[(size_t)(n0 + r) * K + k0 + cc];
        }
        __syncthreads();
        s8v af[4], bf[4];
        #pragma unroll
        for (int i = 0; i < 4; ++i)
            af[i] = *(const s8v*)&Alds[(wm * 64 + i * 16 + m16) * 40 + quad * 8];
        #pragma unroll
        for (int i = 0; i < 4; ++i)
            bf[i] = *(const s8v*)&Blds[(wn * 64 + i * 16 + m16) * 40 + quad * 8];
        #pragma unroll
        for (int i = 0; i < 4; ++i)
            #pragma unroll
            for (int nj = 0; nj < 4; ++nj)
                acc[i][nj] = __builtin_amdgcn_mfma_f32_16x16x32_bf16(
                    af[i], bf[nj], acc[i][nj], 0, 0, 0);
        __syncthreads();
    }
    #pragma unroll
    for (int nj = 0; nj < 4; ++nj) {
        int col = n0 + wn * 64 + nj * 16 + m16;
        float bv = bias[col];
        #pragma unroll
        for (int i = 0; i < 4; ++i)
            #pragma unroll
            for (int r = 0; r < 4; ++r) {
                int row = m0 + wm * 64 + i * 16 + quad * 4 + r;
                float v = acc[i][nj][r] + bv;
                C[(size_t)row * ldc + colofs + col] = (EPI == 0) ? f2bf(v) : f2h(v);
            }
    }
}

// ---------------------------------------------------------------------------
// LSTM over T=1024 via broadcast-A i8 MFMA GEMV. One block per batch, 256
// thr (4 waves, 1/SIMD, 512-reg budget). Wave w owns h-cols [w*64, w*64+64).
// Ul FULLY register-resident as i8 (per-column-scaled): 64 frags x 4 regs =
// exactly 256 AGPRs. h recurrence state quantized to i8 (scale 127, |h|<1);
// K=64 per MFMA halves the matrix-pipe issue cycles vs f16 K=32 (the r6
// bottleneck: 2480 cy/step of MFMA issue -> ~1310). i32 accumulation is
// exact; dequant = one mul with per-lane/gate constant dq[n]=cm[n]/127^2.
// LDS carries only h (512 B): 4 broadcast b128 reads + 1 byte write/lane.
// Per-step barrier: s_waitcnt lgkmcnt(0) + s_barrier (vmem stays in flight).
// ---------------------------------------------------------------------------
#define PAIR_BODY(CGA, CGB)                                            \
    {                                                                  \
        i4v A0, A1, A2, A3, B0, B1, B2, B3;                            \
        MFMA_I8_INIT(A0, av[0], wa[CGA][0][0], zi);                    \
        MFMA_I8_INIT(A1, av[0], wa[CGA][1][0], zi);                    \
        MFMA_I8_INIT(A2, av[0], wa[CGA][2][0], zi);                    \
        MFMA_I8_INIT(A3, av[0], wa[CGA][3][0], zi);                    \
        MFMA_I8_INIT(B0, av[0], wa[CGB][0][0], zi);                    \
        MFMA_I8_INIT(B1, av[0], wa[CGB][1][0], zi);                    \
        MFMA_I8_INIT(B2, av[0], wa[CGB][2][0], zi);                    \
        MFMA_I8_INIT(B3, av[0], wa[CGB][3][0], zi);                    \
        _Pragma("unroll")                                              \
        for (int kt = 1; kt < 4; ++kt) {                               \
            MFMA_I8(A0, av[kt], wa[CGA][0][kt]);                       \
            MFMA_I8(A1, av[kt], wa[CGA][1][kt]);                       \
            MFMA_I8(A2, av[kt], wa[CGA][2][kt]);                       \
            MFMA_I8(A3, av[kt], wa[CGA][3][kt]);                       \
            MFMA_I8(B0, av[kt], wa[CGB][0][kt]);                       \
            MFMA_I8(B1, av[kt], wa[CGB][1][kt]);                       \
            MFMA_I8(B2, av[kt], wa[CGB][2][kt]);                       \
            MFMA_I8(B3, av[kt], wa[CGB][3][kt]);                       \
        }                                                              \
        asm volatile("s_nop 7\n\ts_nop 7");                            \
        zq0 = (quad == CGA) ? A0[0] : ((quad == CGB) ? B0[0] : zq0);   \
        zq1 = (quad == CGA) ? A1[0] : ((quad == CGB) ? B1[0] : zq1);   \
        zq2 = (quad == CGA) ? A2[0] : ((quad == CGB) ? B2[0] : zq2);   \
        zq3 = (quad == CGA) ? A3[0] : ((quad == CGB) ? B3[0] : zq3);   \
    }

__global__ __launch_bounds__(256, 1) void lstm_kernel(const f16* __restrict__ pre,
                                                      const u16* __restrict__ ulB,
                                                      const float* __restrict__ dq,
                                                      u16* __restrict__ hout)
{
    __shared__ __align__(16) char hl8[2][256];   // i8 h state, double buffer
    const int tid = threadIdx.x, b = blockIdx.x;
    const int w = tid >> 6, lane = tid & 63, quad = lane >> 4;

    const i4v* ub = (const i4v*)ulB;
    // all 64 i8 frags pinned in AGPRs (one-time copy; exactly 256 AGPRs)
    i4v wa[4][4][4];
    #pragma unroll
    for (int cg = 0; cg < 4; ++cg)
        #pragma unroll
        for (int g = 0; g < 4; ++g)
            #pragma unroll
            for (int kt = 0; kt < 4; ++kt) {
                i4v tmp = ub[(size_t)(((w * 16 + cg * 4 + g) * 4 + kt) * 64 + lane)];
                asm("" : "=a"(wa[cg][g][kt]) : "0"(tmp));
            }
    // per-lane/gate dequant constants (column n = g*256 + tid)
    float dqv[4];
    #pragma unroll
    for (int g = 0; g < 4; ++g) dqv[g] = dq[g * 256 + tid];

    const f16* prep_ = pre + (size_t)b * 1024 * 1024;
    const f16* pcol = prep_ + tid;          // lane's column stream (col = tid)
    u16* ho = hout + (size_t)b * 1024 * 256;
    hl8[0][tid] = 0;
    float c = 0.f;
    f16 pcur[4];
    #pragma unroll
    for (int g = 0; g < 4; ++g) pcur[g] = pcol[g * 256];
    i4v zi = {0, 0, 0, 0};
    __syncthreads();

    #pragma unroll 1
    for (int t = 0; t < 1024; ++t) {
        const int cur = t & 1;
        // h k-slices for this quad (broadcast LDS reads, 16B each)
        i4v av[4];
        #pragma unroll
        for (int kt = 0; kt < 4; ++kt)
            av[kt] = *(const i4v*)&hl8[cur][kt * 64 + quad * 16];
        // prefetch pre[t+1] (stays in flight across the barrier)
        int t1 = (t < 1023) ? (t + 1) : 1023;
        f16 pnext[4];
        #pragma unroll
        for (int g = 0; g < 4; ++g) pnext[g] = pcol[(size_t)t1 * 1024 + g * 256];

        int zq0 = 0, zq1 = 0, zq2 = 0, zq3 = 0;
        PAIR_BODY(0, 1);
        PAIR_BODY(2, 3);

        // gates, once per lane (column = tid; cg == quad selected above)
        float z0 = (float)zq0 * dqv[0] + (float)pcur[0];
        float z1 = (float)zq1 * dqv[1] + (float)pcur[1];
        float z2 = (float)zq2 * dqv[2] + (float)pcur[2];
        float z3 = (float)zq3 * dqv[3] + (float)pcur[3];
        float ig = sigm(z0), fg = sigm(z1);
        float gg = fast_tanh(z2), og = sigm(z3);
        c = fg * c + ig * gg;
        float hs = og * fast_tanh(c);
        int hq = (int)rintf(hs * 127.f);            // |hs| < 1 -> no clamp
        hl8[cur ^ 1][tid] = (char)hq;
        ho[(size_t)t * 256 + tid] = f2bf(hs);       // fire-and-forget
        #pragma unroll
        for (int g = 0; g < 4; ++g) pcur[g] = pnext[g];
        // raw barrier: drain LDS only; vmem ops continue across
        asm volatile("s_waitcnt lgkmcnt(0)\n\ts_barrier" ::: "memory");
    }
}

// ---------------------------------------------------------------------------
// out[row] = sum_n sigmoid(h[row]@Wo[:,n] + bo[n]) * q[row,n]
// ---------------------------------------------------------------------------
__global__ __launch_bounds__(256) void gemm_out(const u16* __restrict__ H,
                                                const u16* __restrict__ woT,
                                                const float* __restrict__ bo,
                                                const float* __restrict__ q,
                                                float* __restrict__ out)
{
    __shared__ u16 Alds[64 * 40];
    __shared__ u16 Blds[256 * 40];
    __shared__ float red[64][4];
    int tid = threadIdx.x;
    int m0 = blockIdx.x * 64;
    int lane = tid & 63, w = tid >> 6, quad = lane >> 4, m16 = lane & 15;
    f4v acc[4][4];
    #pragma unroll
    for (int i = 0; i < 4; ++i)
        #pragma unroll
        for (int j = 0; j < 4; ++j) acc[i][j] = (f4v){0.f, 0.f, 0.f, 0.f};

    for (int k0 = 0; k0 < 256; k0 += 32) {
        {
            int e = tid * 8;
            int r = e >> 5, cc = e & 31;
            *(uint4*)&Alds[r * 40 + cc] =
                *(const uint4*)&H[(size_t)(m0 + r) * 256 + k0 + cc];
        }
        #pragma unroll
        for (int p = 0; p < 4; ++p) {
            int e = (p * 256 + tid) * 8;
            int r = e >> 5, cc = e & 31;
            *(uint4*)&Blds[r * 40 + cc] =
                *(const uint4*)&woT[(size_t)r * 256 + k0 + cc];
        }
        __syncthreads();
        s8v af[4], bf[4];
        #pragma unroll
        for (int i = 0; i < 4; ++i)
            af[i] = *(const s8v*)&Alds[(i * 16 + m16) * 40 + quad * 8];
        #pragma unroll
        for (int i = 0; i < 4; ++i)
            bf[i] = *(const s8v*)&Blds[(w * 64 + i * 16 + m16) * 40 + quad * 8];
        #pragma unroll
        for (int i = 0; i < 4; ++i)
            #pragma unroll
            for (int nj = 0; nj < 4; ++nj)
                acc[i][nj] = __builtin_amdgcn_mfma_f32_16x16x32_bf16(
                    af[i], bf[nj], acc[i][nj], 0, 0, 0);
        __syncthreads();
    }
    float rsum[4][4];
    #pragma unroll
    for (int i = 0; i < 4; ++i)
        #pragma unroll
        for (int r = 0; r < 4; ++r) rsum[i][r] = 0.f;
    #pragma unroll
    for (int nj = 0; nj < 4; ++nj) {
        int col = w * 64 + nj * 16 + m16;
        float bv = bo[col];
        #pragma unroll
        for (int i = 0; i < 4; ++i)
            #pragma unroll
            for (int r = 0; r < 4; ++r) {
                int row = m0 + i * 16 + quad * 4 + r;
                float v = sigm(acc[i][nj][r] + bv);
                rsum[i][r] += v * q[(size_t)row * 256 + col];
            }
    }
    #pragma unroll
    for (int d = 1; d <= 8; d <<= 1)
        #pragma unroll
        for (int i = 0; i < 4; ++i)
            #pragma unroll
            for (int r = 0; r < 4; ++r) rsum[i][r] += __shfl_xor(rsum[i][r], d);
    if (m16 == 0) {
        #pragma unroll
        for (int i = 0; i < 4; ++i)
            #pragma unroll
            for (int r = 0; r < 4; ++r)
                red[i * 16 + quad * 4 + r][w] = rsum[i][r];
    }
    __syncthreads();
    if (tid < 64)
        out[m0 + tid] = red[tid][0] + red[tid][1] + red[tid][2] + red[tid][3];
}

// ---------------------------------------------------------------------------
extern "C" void kernel_launch(void* const* d_in, const int* in_sizes, int n_in,
                              void* d_out, int out_size, void* d_ws, size_t ws_size,
                              hipStream_t stream)
{
    (void)in_sizes; (void)n_in; (void)out_size; (void)ws_size;
    const float* x     = (const float*)d_in[0];
    const float* delta = (const float*)d_in[1];
    const float* q     = (const float*)d_in[2];
    const float* Wx    = (const float*)d_in[3];
    const float* bx    = (const float*)d_in[4];
    const float* Wc    = (const float*)d_in[5];
    const float* bc    = (const float*)d_in[6];
    const float* Wd    = (const float*)d_in[7];
    const float* bd    = (const float*)d_in[8];
    const float* Wl    = (const float*)d_in[9];
    const float* Ul    = (const float*)d_in[10];
    const float* bl    = (const float*)d_in[11];
    const float* Wo    = (const float*)d_in[12];
    const float* bo    = (const float*)d_in[13];

    char* ws = (char*)d_ws;
    float* s_buf = (float*)(ws + 0);            // 256 KB
    u16* ulB     = (u16*)(ws + 262144);         // 256 KB (i8 B-frag layout)
    float* cm    = (float*)(ws + 524288);       // 4 KB per-column |Ul| max
    float* dq    = (float*)(ws + 528384);       // 4 KB dequant consts
    u16* wxT     = (u16*)(ws + 786432);         // 128 KB
    u16* wcT     = (u16*)(ws + 917504);         // 128 KB
    u16* wlT     = (u16*)(ws + 1048576);        // 576 KB
    u16* woT     = (u16*)(ws + 1638400);        // 128 KB
    u16* xc      = (u16*)(ws + 1769472);        // 36 MB  [65536 x 288] bf16
    u16* hbuf    = (u16*)(ws + 39518208);       // 32 MB  [65536 x 256] bf16
    u16* xbf     = (u16*)(ws + 73072640);       // 64 MB  bf16 copy of x
    u16* clog    = (u16*)(ws + 140181504);      // 64 MB  log1p(counts) bf16
    f16* pre     = (f16*)(ws + 73072640);       // 128 MB f16, aliases xbf+clog
    // count-scan scratch lives in the (not yet used) hbuf region
    float* cend  = (float*)hbuf;                // 1 MB
    float* cin   = (float*)(ws + 39518208 + (1 << 20));   // 1 MB
    float* Pq    = (float*)(ws + 39518208 + (2 << 20));   // 2 KB

    colmax<<<4, 256, 0, stream>>>(Ul, cm, dq);
    prep_kernel<<<2048, 256, 0, stream>>>(Wx, Wc, Wl, Wo, Ul, cm,
                                          wxT, wcT, wlT, woT, ulB);
    row_sums<<<16384, 256, 0, stream>>>((const float4*)x, s_buf);
    count_phaseA<<<512, 512, 0, stream>>>(x, s_buf, cend, Pq);
    count_phaseB<<<64, 512, 0, stream>>>(cend, Pq, cin);
    count_phaseC<<<512, 512, 0, stream>>>(x, s_buf, cin, xbf, clog);
    fill_xc<<<8192, 256, 0, stream>>>(delta, Wd, bd, xc);
    gemm128<0><<<dim3(512, 1), 256, 0, stream>>>(xbf, wxT, bx, xc, 512, 288, 0);
    gemm128<0><<<dim3(512, 1), 256, 0, stream>>>(clog, wcT, bc, xc, 512, 288, 128);
    gemm128<1><<<dim3(512, 8), 256, 0, stream>>>(xc, wlT, bl, (u16*)pre, 288, 1024, 0);
    lstm_kernel<<<64, 256, 0, stream>>>(pre, ulB, dq, hbuf);
    gemm_out<<<1024, 256, 0, stream>>>(hbuf, woT, bo, q, (float*)d_out);
}

// Round 10
// 1373.302 us; speedup vs baseline: 4.6795x; 1.0300x over previous
//
#include <hip/hip_runtime.h>
#include <hip/hip_bf16.h>

typedef unsigned short u16;
typedef _Float16 f16;
typedef _Float16 f16x8 __attribute__((ext_vector_type(8)));
typedef short s8v __attribute__((ext_vector_type(8)));
typedef float f4v __attribute__((ext_vector_type(4)));
typedef int i4v __attribute__((ext_vector_type(4)));

__device__ __forceinline__ u16 f2bf(float f) {
    union { float f; unsigned u; } v; v.f = f;
    unsigned r = v.u + 0x7FFF + ((v.u >> 16) & 1);
    return (u16)(r >> 16);
}
__device__ __forceinline__ u16 f2h(float f) {
    f16 h = (f16)f;
    union { f16 h; u16 u; } v; v.h = h;
    return v.u;
}
__device__ __forceinline__ float rcpf(float x) { return __builtin_amdgcn_rcpf(x); }
__device__ __forceinline__ float sigm(float x) { return rcpf(1.f + __expf(-x)); }
__device__ __forceinline__ float fast_tanh(float x) {
    float ax = fabsf(x);
    float e = __expf(2.f * ax);
    float r = 1.f - 2.f * rcpf(e + 1.f);   // overflow-safe: e=inf -> r=1
    return copysignf(r, x);
}

// Inline-asm i8 MFMA (K=64). A from VGPR (broadcast h), B from AGPR
// (resident weights), i32 acc. INIT uses EARLY-CLOBBER "=&v": MFMA D must
// never overlap A/B (HW hazard; r7 container death signature).
#define MFMA_I8_INIT(D, A, B, C) \
    asm volatile("v_mfma_i32_16x16x64_i8 %0, %1, %2, %3" \
                 : "=&v"(D) : "v"(A), "a"(B), "v"(C))
#define MFMA_I8(D, A, B) \
    asm volatile("v_mfma_i32_16x16x64_i8 %0, %1, %2, %0" \
                 : "+v"(D) : "v"(A), "a"(B))

#define SB __builtin_amdgcn_sched_barrier(0)

// gate-major issue groups: one kt-slot of 8 chains (gates GA,GB x cg 0..3)
#define GG_K0(A0,A1,A2,A3,B0,B1,B2,B3, GA, GB)     \
    MFMA_I8_INIT(A0, av[0], wa[0][GA][0], zi);     \
    MFMA_I8_INIT(A1, av[0], wa[1][GA][0], zi);     \
    MFMA_I8_INIT(A2, av[0], wa[2][GA][0], zi);     \
    MFMA_I8_INIT(A3, av[0], wa[3][GA][0], zi);     \
    MFMA_I8_INIT(B0, av[0], wa[0][GB][0], zi);     \
    MFMA_I8_INIT(B1, av[0], wa[1][GB][0], zi);     \
    MFMA_I8_INIT(B2, av[0], wa[2][GB][0], zi);     \
    MFMA_I8_INIT(B3, av[0], wa[3][GB][0], zi);
#define GG_KT(A0,A1,A2,A3,B0,B1,B2,B3, GA, GB, KT) \
    MFMA_I8(A0, av[KT], wa[0][GA][KT]);            \
    MFMA_I8(A1, av[KT], wa[1][GA][KT]);            \
    MFMA_I8(A2, av[KT], wa[2][GA][KT]);            \
    MFMA_I8(A3, av[KT], wa[3][GA][KT]);            \
    MFMA_I8(B0, av[KT], wa[0][GB][KT]);            \
    MFMA_I8(B1, av[KT], wa[1][GB][KT]);            \
    MFMA_I8(B2, av[KT], wa[2][GB][KT]);            \
    MFMA_I8(B3, av[KT], wa[3][GB][KT]);

#define SEL4(C0,C1,C2,C3) \
    ((quad == 0) ? (float)C0[0] : (quad == 1) ? (float)C1[0] : \
     (quad == 2) ? (float)C2[0] : (float)C3[0])

// ---------------------------------------------------------------------------
// Per-column |Ul| max -> quant scale (prep input) and dequant const (lstm).
// ---------------------------------------------------------------------------
__global__ __launch_bounds__(256) void colmax(const float* __restrict__ Ul,
                                              float* __restrict__ cm,
                                              float* __restrict__ dq)
{
    int n = blockIdx.x * 256 + threadIdx.x;   // [0,1024)
    float m = 0.f;
    for (int k = 0; k < 256; ++k) m = fmaxf(m, fabsf(Ul[(size_t)k * 1024 + n]));
    m = fmaxf(m, 1e-8f);
    cm[n] = m;
    dq[n] = m / 16129.0f;                     // m / (127*127)
}

// ---------------------------------------------------------------------------
// Weight prep: transposes to [N][K] bf16 for MFMA B-operand for the GEMMs,
// and packs Ul as i8 MFMA B-frags (16x16x64) with per-column scale 127/cm[n]:
//   256 frags, F = (w*16 + cg*4 + g)*4 + kt; lane l holds 16 bytes:
//     k = kt*64 + (l>>4)*16 + j (j 0..15),  n = g*256 + w*64 + cg*16 + (l&15)
//   A (h) and B use the same lane->k mapping, so any HW k-permutation
//   cancels; per-column dequant applied after accumulation.
// ---------------------------------------------------------------------------
__global__ __launch_bounds__(256) void prep_kernel(
    const float* __restrict__ Wx, const float* __restrict__ Wc,
    const float* __restrict__ Wl, const float* __restrict__ Wo,
    const float* __restrict__ Ul, const float* __restrict__ cm,
    u16* __restrict__ wxT, u16* __restrict__ wcT, u16* __restrict__ wlT,
    u16* __restrict__ woT, u16* __restrict__ ulB)
{
    int i = blockIdx.x * 256 + threadIdx.x;
    if (i < 65536) {                    // WxT[n][k] : 128x512
        int n = i >> 9, k = i & 511;
        wxT[i] = f2bf(Wx[k * 128 + n]);
    } else if (i < 131072) {            // WcT
        int t = i - 65536;
        int n = t >> 9, k = t & 511;
        wcT[t] = f2bf(Wc[k * 128 + n]);
    } else if (i < 425984) {            // WlT[n][k] : 1024x288 (K padded 257->288)
        int t = i - 131072;
        int n = t / 288, k = t % 288;
        wlT[t] = (k < 257) ? f2bf(Wl[k * 1024 + n]) : (u16)0;
    } else if (i < 491520) {            // WoT[n][k] : 256x256
        int t = i - 425984;
        int n = t >> 8, k = t & 255;
        woT[t] = f2bf(Wo[k * 256 + n]);
    } else {                            // ulB i8 frags, i in [491520, 524288)
        int e = i - 491520;             // [0, 32768): 8 bytes each
        int fg = e >> 7, rem = e & 127;
        int lane = rem >> 1, hf = rem & 1;
        int w = fg >> 6, t2 = fg & 63, tile = t2 >> 2, kt = t2 & 3;
        int cg = tile >> 2, g = tile & 3;
        int m16 = lane & 15, quad = lane >> 4;
        int n = g * 256 + w * 64 + cg * 16 + m16;
        int kb = kt * 64 + quad * 16 + hf * 8;
        float sw = 127.0f / cm[n];
        char* o = (char*)ulB + ((size_t)(fg * 64 + lane) * 16 + hf * 8);
        #pragma unroll
        for (int jj = 0; jj < 8; ++jj) {
            float v = Ul[(size_t)(kb + jj) * 1024 + n] * sw;
            int bq = (int)rintf(v);
            bq = bq > 127 ? 127 : (bq < -127 ? -127 : bq);
            o[jj] = (char)bq;
        }
    }
}

// ---------------------------------------------------------------------------
// s[b,t] = sum_k x[b,t,k]   (one wave per row)
// ---------------------------------------------------------------------------
__global__ __launch_bounds__(256) void row_sums(const float4* __restrict__ x4,
                                                float* __restrict__ s)
{
    int w = threadIdx.x >> 6, lane = threadIdx.x & 63;
    size_t row = (size_t)blockIdx.x * 4 + w;
    const float4* r = x4 + row * 128;
    float4 a = r[lane], b = r[64 + lane];
    float sum = a.x + a.y + a.z + a.w + b.x + b.y + b.z + b.w;
    #pragma unroll
    for (int d = 32; d >= 1; d >>= 1) sum += __shfl_xor(sum, d);
    if (lane == 0) s[row] = sum;
}

// ---------------------------------------------------------------------------
// Count recurrence, 3-phase chunked (8 chunks of 128 steps per batch).
// ---------------------------------------------------------------------------
__global__ __launch_bounds__(512) void count_phaseA(const float* __restrict__ x,
                                                    const float* __restrict__ s,
                                                    float* __restrict__ cend,
                                                    float* __restrict__ Pq)
{
    int k = threadIdx.x, bi = blockIdx.x;
    int b = bi >> 3, qc = bi & 7;
    const float* xb = x + ((size_t)b * 1024 + qc * 128) * 512;
    const float* sb = s + b * 1024 + qc * 128;
    float c = 0.f, P = 1.f;
    for (int t0 = 0; t0 < 128; t0 += 8) {
        float xv[8], sv[8];
        #pragma unroll
        for (int i = 0; i < 8; ++i) {
            xv[i] = xb[(size_t)(t0 + i) * 512 + k];
            sv[i] = sb[t0 + i];
        }
        #pragma unroll
        for (int i = 0; i < 8; ++i) { c = sv[i] * c + xv[i]; P *= sv[i]; }
    }
    cend[(size_t)bi * 512 + k] = c;
    if (k == 0) Pq[bi] = P;
}

__global__ __launch_bounds__(512) void count_phaseB(const float* __restrict__ cend,
                                                    const float* __restrict__ Pq,
                                                    float* __restrict__ cin)
{
    int k = threadIdx.x, b = blockIdx.x;
    float c = 0.f;
    for (int q = 0; q < 8; ++q) {
        int bi = b * 8 + q;
        cin[(size_t)bi * 512 + k] = c;
        c = Pq[bi] * c + cend[(size_t)bi * 512 + k];
    }
}

__global__ __launch_bounds__(512) void count_phaseC(const float* __restrict__ x,
                                                    const float* __restrict__ s,
                                                    const float* __restrict__ cin,
                                                    u16* __restrict__ xbf,
                                                    u16* __restrict__ clog)
{
    int k = threadIdx.x, bi = blockIdx.x;
    int b = bi >> 3, qc = bi & 7;
    size_t base = ((size_t)b * 1024 + qc * 128) * 512;
    const float* xb = x + base;
    const float* sb = s + b * 1024 + qc * 128;
    u16* xo = xbf + base;
    u16* co = clog + base;
    float c = cin[(size_t)bi * 512 + k];
    for (int t0 = 0; t0 < 128; t0 += 8) {
        float xv[8], sv[8];
        #pragma unroll
        for (int i = 0; i < 8; ++i) {
            xv[i] = xb[(size_t)(t0 + i) * 512 + k];
            sv[i] = sb[t0 + i];
        }
        #pragma unroll
        for (int i = 0; i < 8; ++i) {
            c = sv[i] * c + xv[i];
            size_t idx = (size_t)(t0 + i) * 512 + k;
            xo[idx] = f2bf(xv[i]);
            co[idx] = f2bf(log1pf(c));
        }
    }
}

// ---------------------------------------------------------------------------
// xc[:,256] = exp(-(delta*Wd+bd)); xc[:,257:288] = 0
// ---------------------------------------------------------------------------
__global__ __launch_bounds__(256) void fill_xc(const float* __restrict__ delta,
                                               const float* __restrict__ Wd,
                                               const float* __restrict__ bd,
                                               u16* __restrict__ xc)
{
    int i = blockIdx.x * 256 + threadIdx.x;   // 65536*32
    int row = i >> 5, cc = i & 31;
    float v = 0.f;
    if (cc == 0) v = __expf(-(delta[row] * Wd[0] + bd[0]));
    xc[(size_t)row * 288 + 256 + cc] = f2bf(v);
}

// ---------------------------------------------------------------------------
// Generic 128x128-tile bf16 MFMA GEMM: C[row, colofs+col] = A@B + bias.
// ---------------------------------------------------------------------------
template <int EPI>
__global__ __launch_bounds__(256) void gemm128(const u16* __restrict__ A,
                                               const u16* __restrict__ BT,
                                               const float* __restrict__ bias,
                                               u16* __restrict__ C,
                                               int K, int ldc, int colofs)
{
    __shared__ u16 Alds[128 * 40];
    __shared__ u16 Blds[128 * 40];
    int tid = threadIdx.x;
    int m0 = blockIdx.x * 128, n0 = blockIdx.y * 128;
    int lane = tid & 63, w = tid >> 6, quad = lane >> 4, m16 = lane & 15;
    int wm = w & 1, wn = w >> 1;
    f4v acc[4][4];
    #pragma unroll
    for (int i = 0; i < 4; ++i)
        #pragma unroll
        for (int j = 0; j < 4; ++j) acc[i][j] = (f4v){0.f, 0.f, 0.f, 0.f};

    for (int k0 = 0; k0 < K; k0 += 32) {
        #pragma unroll
        for (int p = 0; p < 2; ++p) {
            int e = (p * 256 + tid) * 8;
            int r = e >> 5, cc = e & 31;
            *(uint4*)&Alds[r * 40 + cc] =
                *(const uint4*)&A[(size_t)(m0 + r) * K + k0 + cc];
            *(uint4*)&Blds[r * 40 + cc] =
                *(const uint4*)&BT[(size_t)(n0 + r) * K + k0 + cc];
        }
        __syncthreads();
        s8v af[4], bf[4];
        #pragma unroll
        for (int i = 0; i < 4; ++i)
            af[i] = *(const s8v*)&Alds[(wm * 64 + i * 16 + m16) * 40 + quad * 8];
        #pragma unroll
        for (int i = 0; i < 4; ++i)
            bf[i] = *(const s8v*)&Blds[(wn * 64 + i * 16 + m16) * 40 + quad * 8];
        #pragma unroll
        for (int i = 0; i < 4; ++i)
            #pragma unroll
            for (int nj = 0; nj < 4; ++nj)
                acc[i][nj] = __builtin_amdgcn_mfma_f32_16x16x32_bf16(
                    af[i], bf[nj], acc[i][nj], 0, 0, 0);
        __syncthreads();
    }
    #pragma unroll
    for (int nj = 0; nj < 4; ++nj) {
        int col = n0 + wn * 64 + nj * 16 + m16;
        float bv = bias[col];
        #pragma unroll
        for (int i = 0; i < 4; ++i)
            #pragma unroll
            for (int r = 0; r < 4; ++r) {
                int row = m0 + wm * 64 + i * 16 + quad * 4 + r;
                float v = acc[i][nj][r] + bv;
                C[(size_t)row * ldc + colofs + col] = (EPI == 0) ? f2bf(v) : f2h(v);
            }
    }
}

// ---------------------------------------------------------------------------
// LSTM over T=1024 via broadcast-A i8 MFMA GEMV. One block per batch, 256
// thr (4 waves, 1/SIMD). Wave w owns h-cols [w*64, w*64+64). Ul fully
// register-resident as i8 (64 frags = exactly 256 AGPRs; per-column scale).
// GATE-MAJOR chain order + VALU interleave: gates (0,1) = 8 chains x 4 kt,
// then gates (2,3); gates 0/1 finish after the first 32 MFMAs, so their
// select/dequant/exp/rcp VALU is placed BETWEEN the kt-groups of gates
// 2/3's MFMAs (sched_barrier(0)-pinned) and issues for free in the matrix
// pipe's backpressure stall gaps. Only gates 2/3 + h update remain in the
// serial tail. Per-step barrier: s_waitcnt lgkmcnt(0) + s_barrier.
// ---------------------------------------------------------------------------
__global__ __launch_bounds__(256, 1) void lstm_kernel(const f16* __restrict__ pre,
                                                      const u16* __restrict__ ulB,
                                                      const float* __restrict__ dq,
                                                      u16* __restrict__ hout)
{
    __shared__ __align__(16) char hl8[2][256];   // i8 h state, double buffer
    const int tid = threadIdx.x, b = blockIdx.x;
    const int w = tid >> 6, lane = tid & 63, quad = lane >> 4;

    const i4v* ub = (const i4v*)ulB;
    // all 64 i8 frags pinned in AGPRs (one-time copy; exactly 256 AGPRs)
    i4v wa[4][4][4];
    #pragma unroll
    for (int cg = 0; cg < 4; ++cg)
        #pragma unroll
        for (int g = 0; g < 4; ++g)
            #pragma unroll
            for (int kt = 0; kt < 4; ++kt) {
                i4v tmp = ub[(size_t)(((w * 16 + cg * 4 + g) * 4 + kt) * 64 + lane)];
                asm("" : "=a"(wa[cg][g][kt]) : "0"(tmp));
            }
    // per-lane/gate dequant constants (column n = g*256 + tid)
    float dqv[4];
    #pragma unroll
    for (int g = 0; g < 4; ++g) dqv[g] = dq[g * 256 + tid];

    const f16* prep_ = pre + (size_t)b * 1024 * 1024;
    const f16* pcol = prep_ + tid;          // lane's column stream (col = tid)
    u16* ho = hout + (size_t)b * 1024 * 256;
    hl8[0][tid] = 0;
    float c = 0.f;
    f16 pcur[4];
    #pragma unroll
    for (int g = 0; g < 4; ++g) pcur[g] = pcol[g * 256];
    i4v zi = {0, 0, 0, 0};
    __syncthreads();

    #pragma unroll 1
    for (int t = 0; t < 1024; ++t) {
        const int cur = t & 1;
        // h k-slices for this quad (broadcast LDS reads, 16B each)
        i4v av[4];
        #pragma unroll
        for (int kt = 0; kt < 4; ++kt)
            av[kt] = *(const i4v*)&hl8[cur][kt * 64 + quad * 16];
        // prefetch pre[t+1] (stays in flight across the barrier)
        int t1 = (t < 1023) ? (t + 1) : 1023;
        f16 pnext[4];
        #pragma unroll
        for (int g = 0; g < 4; ++g) pnext[g] = pcol[(size_t)t1 * 1024 + g * 256];

        // ---- gates 0,1: 8 chains x 4 kt (32 MFMAs) ----
        i4v a00, a01, a02, a03, b00, b01, b02, b03;
        GG_K0(a00, a01, a02, a03, b00, b01, b02, b03, 0, 1);
        float pf0 = (float)pcur[0], pf1 = (float)pcur[1];
        SB;
        GG_KT(a00, a01, a02, a03, b00, b01, b02, b03, 0, 1, 1);
        float pf2 = (float)pcur[2], pf3 = (float)pcur[3];
        SB;
        GG_KT(a00, a01, a02, a03, b00, b01, b02, b03, 0, 1, 2);
        SB;
        GG_KT(a00, a01, a02, a03, b00, b01, b02, b03, 0, 1, 3);
        SB;
        // ---- gates 2,3 MFMAs with gates 0,1 VALU in the stall gaps ----
        i4v a10, a11, a12, a13, b10, b11, b12, b13;
        GG_K0(a10, a11, a12, a13, b10, b11, b12, b13, 2, 3);
        SB;
        float z0 = SEL4(a00, a01, a02, a03) * dqv[0] + pf0;
        SB;
        GG_KT(a10, a11, a12, a13, b10, b11, b12, b13, 2, 3, 1);
        SB;
        float ig = rcpf(1.f + __expf(-z0));
        float z1 = SEL4(b00, b01, b02, b03) * dqv[1] + pf1;
        SB;
        GG_KT(a10, a11, a12, a13, b10, b11, b12, b13, 2, 3, 2);
        SB;
        float fg = rcpf(1.f + __expf(-z1));
        SB;
        GG_KT(a10, a11, a12, a13, b10, b11, b12, b13, 2, 3, 3);
        // ---- tail: gates 2,3 + state update ----
        asm volatile("s_nop 7\n\ts_nop 7");
        float z2 = SEL4(a10, a11, a12, a13) * dqv[2] + pf2;
        float z3 = SEL4(b10, b11, b12, b13) * dqv[3] + pf3;
        float gg = fast_tanh(z2);
        float og = rcpf(1.f + __expf(-z3));
        c = fg * c + ig * gg;
        float hs = og * fast_tanh(c);
        int hq = (int)rintf(hs * 127.f);            // |hs| < 1 -> no clamp
        hl8[cur ^ 1][tid] = (char)hq;
        ho[(size_t)t * 256 + tid] = f2bf(hs);       // fire-and-forget
        #pragma unroll
        for (int g = 0; g < 4; ++g) pcur[g] = pnext[g];
        // raw barrier: drain LDS only; vmem ops continue across
        asm volatile("s_waitcnt lgkmcnt(0)\n\ts_barrier" ::: "memory");
    }
}

// ---------------------------------------------------------------------------
// out[row] = sum_n sigmoid(h[row]@Wo[:,n] + bo[n]) * q[row,n]
// ---------------------------------------------------------------------------
__global__ __launch_bounds__(256) void gemm_out(const u16* __restrict__ H,
                                                const u16* __restrict__ woT,
                                                const float* __restrict__ bo,
                                                const float* __restrict__ q,
                                                float* __restrict__ out)
{
    __shared__ u16 Alds[64 * 40];
    __shared__ u16 Blds[256 * 40];
    __shared__ float red[64][4];
    int tid = threadIdx.x;
    int m0 = blockIdx.x * 64;
    int lane = tid & 63, w = tid >> 6, quad = lane >> 4, m16 = lane & 15;
    f4v acc[4][4];
    #pragma unroll
    for (int i = 0; i < 4; ++i)
        #pragma unroll
        for (int j = 0; j < 4; ++j) acc[i][j] = (f4v){0.f, 0.f, 0.f, 0.f};

    for (int k0 = 0; k0 < 256; k0 += 32) {
        {
            int e = tid * 8;
            int r = e >> 5, cc = e & 31;
            *(uint4*)&Alds[r * 40 + cc] =
                *(const uint4*)&H[(size_t)(m0 + r) * 256 + k0 + cc];
        }
        #pragma unroll
        for (int p = 0; p < 4; ++p) {
            int e = (p * 256 + tid) * 8;
            int r = e >> 5, cc = e & 31;
            *(uint4*)&Blds[r * 40 + cc] =
                *(const uint4*)&woT[(size_t)r * 256 + k0 + cc];
        }
        __syncthreads();
        s8v af[4], bf[4];
        #pragma unroll
        for (int i = 0; i < 4; ++i)
            af[i] = *(const s8v*)&Alds[(i * 16 + m16) * 40 + quad * 8];
        #pragma unroll
        for (int i = 0; i < 4; ++i)
            bf[i] = *(const s8v*)&Blds[(w * 64 + i * 16 + m16) * 40 + quad * 8];
        #pragma unroll
        for (int i = 0; i < 4; ++i)
            #pragma unroll
            for (int nj = 0; nj < 4; ++nj)
                acc[i][nj] = __builtin_amdgcn_mfma_f32_16x16x32_bf16(
                    af[i], bf[nj], acc[i][nj], 0, 0, 0);
        __syncthreads();
    }
    float rsum[4][4];
    #pragma unroll
    for (int i = 0; i < 4; ++i)
        #pragma unroll
        for (int r = 0; r < 4; ++r) rsum[i][r] = 0.f;
    #pragma unroll
    for (int nj = 0; nj < 4; ++nj) {
        int col = w * 64 + nj * 16 + m16;
        float bv = bo[col];
        #pragma unroll
        for (int i = 0; i < 4; ++i)
            #pragma unroll
            for (int r = 0; r < 4; ++r) {
                int row = m0 + i * 16 + quad * 4 + r;
                float v = sigm(acc[i][nj][r] + bv);
                rsum[i][r] += v * q[(size_t)row * 256 + col];
            }
    }
    #pragma unroll
    for (int d = 1; d <= 8; d <<= 1)
        #pragma unroll
        for (int i = 0; i < 4; ++i)
            #pragma unroll
            for (int r = 0; r < 4; ++r) rsum[i][r] += __shfl_xor(rsum[i][r], d);
    if (m16 == 0) {
        #pragma unroll
        for (int i = 0; i < 4; ++i)
            #pragma unroll
            for (int r = 0; r < 4; ++r)
                red[i * 16 + quad * 4 + r][w] = rsum[i][r];
    }
    __syncthreads();
    if (tid < 64)
        out[m0 + tid] = red[tid][0] + red[tid][1] + red[tid][2] + red[tid][3];
}

// ---------------------------------------------------------------------------
extern "C" void kernel_launch(void* const* d_in, const int* in_sizes, int n_in,
                              void* d_out, int out_size, void* d_ws, size_t ws_size,
                              hipStream_t stream)
{
    (void)in_sizes; (void)n_in; (void)out_size; (void)ws_size;
    const float* x     = (const float*)d_in[0];
    const float* delta = (const float*)d_in[1];
    const float* q     = (const float*)d_in[2];
    const float* Wx    = (const float*)d_in[3];
    const float* bx    = (const float*)d_in[4];
    const float* Wc    = (const float*)d_in[5];
    const float* bc    = (const float*)d_in[6];
    const float* Wd    = (const float*)d_in[7];
    const float* bd    = (const float*)d_in[8];
    const float* Wl    = (const float*)d_in[9];
    const float* Ul    = (const float*)d_in[10];
    const float* bl    = (const float*)d_in[11];
    const float* Wo    = (const float*)d_in[12];
    const float* bo    = (const float*)d_in[13];

    char* ws = (char*)d_ws;
    float* s_buf = (float*)(ws + 0);            // 256 KB
    u16* ulB     = (u16*)(ws + 262144);         // 256 KB (i8 B-frag layout)
    float* cm    = (float*)(ws + 524288);       // 4 KB per-column |Ul| max
    float* dq    = (float*)(ws + 528384);       // 4 KB dequant consts
    u16* wxT     = (u16*)(ws + 786432);         // 128 KB
    u16* wcT     = (u16*)(ws + 917504);         // 128 KB
    u16* wlT     = (u16*)(ws + 1048576);        // 576 KB
    u16* woT     = (u16*)(ws + 1638400);        // 128 KB
    u16* xc      = (u16*)(ws + 1769472);        // 36 MB  [65536 x 288] bf16
    u16* hbuf    = (u16*)(ws + 39518208);       // 32 MB  [65536 x 256] bf16
    u16* xbf     = (u16*)(ws + 73072640);       // 64 MB  bf16 copy of x
    u16* clog    = (u16*)(ws + 140181504);      // 64 MB  log1p(counts) bf16
    f16* pre     = (f16*)(ws + 73072640);       // 128 MB f16, aliases xbf+clog
    // count-scan scratch lives in the (not yet used) hbuf region
    float* cend  = (float*)hbuf;                // 1 MB
    float* cin   = (float*)(ws + 39518208 + (1 << 20));   // 1 MB
    float* Pq    = (float*)(ws + 39518208 + (2 << 20));   // 2 KB

    colmax<<<4, 256, 0, stream>>>(Ul, cm, dq);
    prep_kernel<<<2048, 256, 0, stream>>>(Wx, Wc, Wl, Wo, Ul, cm,
                                          wxT, wcT, wlT, woT, ulB);
    row_sums<<<16384, 256, 0, stream>>>((const float4*)x, s_buf);
    count_phaseA<<<512, 512, 0, stream>>>(x, s_buf, cend, Pq);
    count_phaseB<<<64, 512, 0, stream>>>(cend, Pq, cin);
    count_phaseC<<<512, 512, 0, stream>>>(x, s_buf, cin, xbf, clog);
    fill_xc<<<8192, 256, 0, stream>>>(delta, Wd, bd, xc);
    gemm128<0><<<dim3(512, 1), 256, 0, stream>>>(xbf, wxT, bx, xc, 512, 288, 0);
    gemm128<0><<<dim3(512, 1), 256, 0, stream>>>(clog, wcT, bc, xc, 512, 288, 128);
    gemm128<1><<<dim3(512, 8), 256, 0, stream>>>(xc, wlT, bl, (u16*)pre, 288, 1024, 0);
    lstm_kernel<<<64, 256, 0, stream>>>(pre, ulB, dq, hbuf);
    gemm_out<<<1024, 256, 0, stream>>>(hbuf, woT, bo, q, (float*)d_out);
}